// Round 1
// baseline (3606.981 us; speedup 1.0000x reference)
//
#include <hip/hip_runtime.h>
#include <hip/hip_bf16.h>
#include <cstdint>
#include <cstddef>

#define GN 100000
#define GE 3200000

// ---------------- CSR build ----------------

__global__ void k_zero(int* __restrict__ p, int n) {
    int i = blockIdx.x * blockDim.x + threadIdx.x;
    if (i < n) p[i] = 0;
}

__global__ void k_hist(const int* __restrict__ dst, int* __restrict__ cnt, int e) {
    for (int i = blockIdx.x * blockDim.x + threadIdx.x; i < e; i += gridDim.x * blockDim.x)
        atomicAdd(&cnt[dst[i]], 1);
}

// chunk = 512 elements per block of 256 threads
__global__ void k_chunksum(const int* __restrict__ cnt, int* __restrict__ bsum, int n) {
    __shared__ int s[256];
    int b = blockIdx.x, t = threadIdx.x;
    int i0 = b * 512;
    int v = 0;
    int i1 = i0 + t;        if (i1 < n) v += cnt[i1];
    int i2 = i0 + 256 + t;  if (i2 < n) v += cnt[i2];
    s[t] = v; __syncthreads();
    for (int d = 128; d > 0; d >>= 1) {
        if (t < d) s[t] += s[t + d];
        __syncthreads();
    }
    if (t == 0) bsum[b] = s[0];
}

__global__ void k_scanb(const int* __restrict__ bsum, int* __restrict__ boff, int nb,
                        int* __restrict__ row_ptr, int n) {
    if (threadIdx.x == 0 && blockIdx.x == 0) {
        int acc = 0;
        for (int b = 0; b < nb; b++) { boff[b] = acc; acc += bsum[b]; }
        row_ptr[n] = acc;
    }
}

// block of 512 threads, Hillis-Steele inclusive scan -> exclusive + block offset
__global__ void k_scanw(const int* __restrict__ cnt, const int* __restrict__ boff,
                        int* __restrict__ row_ptr, int* __restrict__ cursor, int n) {
    __shared__ int s[512];
    int b = blockIdx.x, t = threadIdx.x;
    int i = b * 512 + t;
    int x = (i < n) ? cnt[i] : 0;
    s[t] = x; __syncthreads();
    for (int d = 1; d < 512; d <<= 1) {
        int v = (t >= d) ? s[t - d] : 0;
        __syncthreads();
        s[t] += v;
        __syncthreads();
    }
    int excl = s[t] - x + boff[b];
    if (i < n) { row_ptr[i] = excl; cursor[i] = excl; }
}

__global__ void k_scatter(const int* __restrict__ src, const int* __restrict__ dst,
                          const float* __restrict__ w, int* __restrict__ cursor,
                          int* __restrict__ ecol, float* __restrict__ ew, int e) {
    for (int i = blockIdx.x * blockDim.x + threadIdx.x; i < e; i += gridDim.x * blockDim.x) {
        int d = dst[i];
        int p = atomicAdd(&cursor[d], 1);
        ecol[p] = src[i];
        ew[p]   = w[i];
    }
}

// ---------------- fp32 GEMM: C[n x m] = A[n x 512] @ W[512 x m] ----------------
// tiles: 128 rows x 64 cols, BK=16; block 256 threads; per-thread 8x4 micro-tile
// blockIdx.x = col tile (so consecutive blocks reuse the A row-panel in L2),
// blockIdx.y = row tile

__global__ __launch_bounds__(256) void k_gemm(const float* __restrict__ A,
                                              const float* __restrict__ W,
                                              float* __restrict__ C, int n, int m) {
    __shared__ float At[16][132];   // [k][row], pad 132 (mod 32 = 4)
    __shared__ float Ws[16][64];    // [k][col]
    int t  = threadIdx.x;
    int r0 = blockIdx.y * 128;
    int c0 = blockIdx.x * 64;
    int ty = t >> 4, tx = t & 15;
    int rB = ty * 8, cB = tx * 4;
    int a_r = t >> 1, a_h = (t & 1) * 8;
    int w_r = t >> 4, w_c = (t & 15) * 4;

    float acc[8][4] = {};

    for (int k0 = 0; k0 < 512; k0 += 16) {
        float4 a0, a1;
        int gr = r0 + a_r;
        if (gr < n) {
            const float* ap = A + (size_t)gr * 512 + k0 + a_h;
            a0 = *(const float4*)ap;
            a1 = *(const float4*)(ap + 4);
        } else {
            a0 = make_float4(0.f, 0.f, 0.f, 0.f); a1 = a0;
        }
        float4 wv = *(const float4*)(W + (size_t)(k0 + w_r) * m + c0 + w_c);

        __syncthreads();  // previous iteration's reads done
        At[a_h + 0][a_r] = a0.x; At[a_h + 1][a_r] = a0.y;
        At[a_h + 2][a_r] = a0.z; At[a_h + 3][a_r] = a0.w;
        At[a_h + 4][a_r] = a1.x; At[a_h + 5][a_r] = a1.y;
        At[a_h + 6][a_r] = a1.z; At[a_h + 7][a_r] = a1.w;
        *(float4*)&Ws[w_r][w_c] = wv;
        __syncthreads();

        #pragma unroll
        for (int kk = 0; kk < 16; ++kk) {
            float4 av0 = *(const float4*)&At[kk][rB];
            float4 av1 = *(const float4*)&At[kk][rB + 4];
            float4 bv  = *(const float4*)&Ws[kk][cB];
            float a[8] = {av0.x, av0.y, av0.z, av0.w, av1.x, av1.y, av1.z, av1.w};
            float bb[4] = {bv.x, bv.y, bv.z, bv.w};
            #pragma unroll
            for (int i = 0; i < 8; i++)
                #pragma unroll
                for (int j = 0; j < 4; j++)
                    acc[i][j] = fmaf(a[i], bb[j], acc[i][j]);
        }
    }

    #pragma unroll
    for (int i = 0; i < 8; i++) {
        int gr = r0 + rB + i;
        if (gr < n) {
            float4 v = make_float4(acc[i][0], acc[i][1], acc[i][2], acc[i][3]);
            *(float4*)(C + (size_t)gr * m + c0 + cB) = v;
        }
    }
}

// ---------------- SpMM K=512 (+bias, +relu), one block per dst row ----------------

__global__ __launch_bounds__(256) void k_spmm512(const int* __restrict__ rowp,
                                                 const int* __restrict__ ecol,
                                                 const float* __restrict__ ew,
                                                 const float* __restrict__ H,
                                                 const float* __restrict__ bias,
                                                 float* __restrict__ out, int relu) {
    int row = blockIdx.x;
    int t = threadIdx.x;                 // 256 threads, each owns 2 cols (float2)
    int s0 = rowp[row], s1 = rowp[row + 1];
    const float2* H2 = (const float2*)H;
    float ax = 0.f, ay = 0.f;
    __shared__ int   lc[256];
    __shared__ float lw[256];
    for (int base = s0; base < s1; base += 256) {
        int nn = s1 - base; if (nn > 256) nn = 256;
        __syncthreads();
        if (t < nn) { lc[t] = ecol[base + t]; lw[t] = ew[base + t]; }
        __syncthreads();
        int e = 0;
        for (; e + 4 <= nn; e += 4) {
            int   c0 = lc[e], c1 = lc[e + 1], c2 = lc[e + 2], c3 = lc[e + 3];
            float w0 = lw[e], w1 = lw[e + 1], w2 = lw[e + 2], w3 = lw[e + 3];
            float2 h0 = H2[(size_t)c0 * 256 + t];
            float2 h1 = H2[(size_t)c1 * 256 + t];
            float2 h2 = H2[(size_t)c2 * 256 + t];
            float2 h3 = H2[(size_t)c3 * 256 + t];
            ax += w0 * h0.x + w1 * h1.x + w2 * h2.x + w3 * h3.x;
            ay += w0 * h0.y + w1 * h1.y + w2 * h2.y + w3 * h3.y;
        }
        for (; e < nn; ++e) {
            float2 h = H2[(size_t)lc[e] * 256 + t];
            ax += lw[e] * h.x; ay += lw[e] * h.y;
        }
    }
    float2 b = ((const float2*)bias)[t];
    ax += b.x; ay += b.y;
    if (relu) { ax = fmaxf(ax, 0.f); ay = fmaxf(ay, 0.f); }
    float2 o; o.x = ax; o.y = ay;
    ((float2*)out)[(size_t)row * 256 + t] = o;
}

// ---------------- SpMM K=64 + bias + softmax, one wave per dst row ----------------

__global__ __launch_bounds__(256) void k_spmm64_softmax(const int* __restrict__ rowp,
                                                        const int* __restrict__ ecol,
                                                        const float* __restrict__ ew,
                                                        const float* __restrict__ H,
                                                        const float* __restrict__ bias,
                                                        float* __restrict__ out, int n) {
    int wid  = threadIdx.x >> 6;
    int lane = threadIdx.x & 63;
    int row  = blockIdx.x * 4 + wid;
    if (row >= n) return;
    int s0 = rowp[row], s1 = rowp[row + 1];
    float acc = 0.f;
    int e = s0;
    for (; e + 2 <= s1; e += 2) {
        int   c0 = ecol[e], c1 = ecol[e + 1];
        float w0 = ew[e],   w1 = ew[e + 1];
        acc += w0 * H[(size_t)c0 * 64 + lane] + w1 * H[(size_t)c1 * 64 + lane];
    }
    if (e < s1) acc += ew[e] * H[(size_t)ecol[e] * 64 + lane];
    acc += bias[lane];
    // wave-wide softmax over the 64 classes
    float m = acc;
    for (int d = 32; d > 0; d >>= 1) m = fmaxf(m, __shfl_xor(m, d));
    float p = __expf(acc - m);
    float s = p;
    for (int d = 32; d > 0; d >>= 1) s += __shfl_xor(s, d);
    out[(size_t)row * 64 + lane] = p / s;
}

// ---------------- launch ----------------

extern "C" void kernel_launch(void* const* d_in, const int* in_sizes, int n_in,
                              void* d_out, int out_size, void* d_ws, size_t ws_size,
                              hipStream_t stream) {
    const float* X    = (const float*)d_in[0];
    const int*   esrc = (const int*)d_in[1];
    const int*   edst = (const int*)d_in[2];
    const float* ewin = (const float*)d_in[3];
    const float* W0   = (const float*)d_in[4];
    const float* b0   = (const float*)d_in[5];
    const float* W1   = (const float*)d_in[6];
    const float* b1   = (const float*)d_in[7];
    const float* W2   = (const float*)d_in[8];
    const float* b2   = (const float*)d_in[9];
    float* out = (float*)d_out;

    const int N = GN;
    const int E = GE;

    uint8_t* p = (uint8_t*)d_ws;
    auto alloc = [&](size_t bytes) -> void* {
        void* r = (void*)p;
        p += (bytes + 255) & ~(size_t)255;
        return r;
    };
    float* bufA    = (float*)alloc((size_t)N * 512 * 4);
    float* bufB    = (float*)alloc((size_t)N * 512 * 4);
    float* bufC    = (float*)alloc((size_t)N * 64 * 4);
    int*   cnt     = (int*)alloc((size_t)N * 4);
    int*   row_ptr = (int*)alloc((size_t)(N + 1) * 4);
    int*   cursor  = (int*)alloc((size_t)N * 4);
    int*   ecol    = (int*)alloc((size_t)E * 4);
    float* ewv     = (float*)alloc((size_t)E * 4);
    int*   bsum    = (int*)alloc(1024 * 4);
    int*   boff    = (int*)alloc(1024 * 4);

    // CSR by dst (rebuilt every call: deterministic work, no cross-call state)
    int nch = (N + 511) / 512;
    k_zero<<<(N + 255) / 256, 256, 0, stream>>>(cnt, N);
    k_hist<<<2048, 256, 0, stream>>>(edst, cnt, E);
    k_chunksum<<<nch, 256, 0, stream>>>(cnt, bsum, N);
    k_scanb<<<1, 64, 0, stream>>>(bsum, boff, nch, row_ptr, N);
    k_scanw<<<nch, 512, 0, stream>>>(cnt, boff, row_ptr, cursor, N);
    k_scatter<<<2048, 256, 0, stream>>>(esrc, edst, ewin, cursor, ecol, ewv, E);

    // layer 1: H = relu(spmm(X @ W0) + b0)
    dim3 g1(512 / 64, (N + 127) / 128);
    k_gemm<<<g1, 256, 0, stream>>>(X, W0, bufA, N, 512);
    k_spmm512<<<N, 256, 0, stream>>>(row_ptr, ecol, ewv, bufA, b0, bufB, 1);

    // layer 2
    k_gemm<<<g1, 256, 0, stream>>>(bufB, W1, bufA, N, 512);
    k_spmm512<<<N, 256, 0, stream>>>(row_ptr, ecol, ewv, bufA, b1, bufB, 1);

    // layer 3 + softmax
    dim3 g3(1, (N + 127) / 128);
    k_gemm<<<g3, 256, 0, stream>>>(bufB, W2, bufC, N, 64);
    k_spmm64_softmax<<<(N + 3) / 4, 256, 0, stream>>>(row_ptr, ecol, ewv, bufC, b2, out, N);
}

// Round 4
// 1909.255 us; speedup vs baseline: 1.8892x; 1.8892x over previous
//
#include <hip/hip_runtime.h>
#include <hip/hip_bf16.h>
#include <cstdint>
#include <cstddef>

#define GN 100000
#define GE 3200000

typedef __attribute__((ext_vector_type(8))) _Float16 f16x8;
typedef __attribute__((ext_vector_type(4))) _Float16 f16x4;
typedef __attribute__((ext_vector_type(4))) float f32x4;

// ---------------- CSR build ----------------

__global__ void k_zero(int* __restrict__ p, int n) {
    int i = blockIdx.x * blockDim.x + threadIdx.x;
    if (i < n) p[i] = 0;
}

__global__ void k_hist(const int* __restrict__ dst, int* __restrict__ cnt, int e) {
    for (int i = blockIdx.x * blockDim.x + threadIdx.x; i < e; i += gridDim.x * blockDim.x)
        atomicAdd(&cnt[dst[i]], 1);
}

__global__ void k_chunksum(const int* __restrict__ cnt, int* __restrict__ bsum, int n) {
    __shared__ int s[256];
    int b = blockIdx.x, t = threadIdx.x;
    int i0 = b * 512;
    int v = 0;
    int i1 = i0 + t;        if (i1 < n) v += cnt[i1];
    int i2 = i0 + 256 + t;  if (i2 < n) v += cnt[i2];
    s[t] = v; __syncthreads();
    for (int d = 128; d > 0; d >>= 1) {
        if (t < d) s[t] += s[t + d];
        __syncthreads();
    }
    if (t == 0) bsum[b] = s[0];
}

__global__ void k_scanb(const int* __restrict__ bsum, int* __restrict__ boff, int nb,
                        int* __restrict__ row_ptr, int n) {
    if (threadIdx.x == 0 && blockIdx.x == 0) {
        int acc = 0;
        for (int b = 0; b < nb; b++) { boff[b] = acc; acc += bsum[b]; }
        row_ptr[n] = acc;
    }
}

__global__ void k_scanw(const int* __restrict__ cnt, const int* __restrict__ boff,
                        int* __restrict__ row_ptr, int* __restrict__ cursor, int n) {
    __shared__ int s[512];
    int b = blockIdx.x, t = threadIdx.x;
    int i = b * 512 + t;
    int x = (i < n) ? cnt[i] : 0;
    s[t] = x; __syncthreads();
    for (int d = 1; d < 512; d <<= 1) {
        int v = (t >= d) ? s[t - d] : 0;
        __syncthreads();
        s[t] += v;
        __syncthreads();
    }
    int excl = s[t] - x + boff[b];
    if (i < n) { row_ptr[i] = excl; cursor[i] = excl; }
}

__global__ void k_scatter(const int* __restrict__ src, const int* __restrict__ dst,
                          const float* __restrict__ w, int* __restrict__ cursor,
                          int* __restrict__ ecol, float* __restrict__ ew, int e) {
    for (int i = blockIdx.x * blockDim.x + threadIdx.x; i < e; i += gridDim.x * blockDim.x) {
        int d = dst[i];
        int p = atomicAdd(&cursor[d], 1);
        ecol[p] = src[i];
        ew[p]   = w[i];
    }
}

// ---------------- W[K][M] fp32 -> split-transposed Wth/Wtl[M][K] fp16 ----------------

__global__ void k_transp_split(const float* __restrict__ W,
                               _Float16* __restrict__ Wth, _Float16* __restrict__ Wtl,
                               int K, int M) {
    __shared__ float tile[32][33];
    int bx = blockIdx.x * 32;  // M dim
    int by = blockIdx.y * 32;  // K dim
    int tx = threadIdx.x, ty = threadIdx.y;
    for (int i = ty; i < 32; i += 8)
        tile[i][tx] = W[(size_t)(by + i) * M + bx + tx];
    __syncthreads();
    for (int i = ty; i < 32; i += 8) {
        float w = tile[tx][i];
        _Float16 h = (_Float16)w;
        _Float16 l = (_Float16)(w - (float)h);
        Wth[(size_t)(bx + i) * K + by + tx] = h;
        Wtl[(size_t)(bx + i) * K + by + tx] = l;
    }
}

// ---------------- split fp16 MFMA GEMM: C[n x m] = A[n x 512] @ Bt^T ----------------
// A row-major fp32 [n][512] (split to hi/lo fp16 on the fly);
// Bth/Btl = W^T hi/lo, row-major fp16 [m][512]; C = OutT [n][m].
// acc = Ah*Bh + Al*Bh + Ah*Bl (fp32 acc) -> effective fp32-level precision.
// Tile 128 x BN, BK=64, 256 threads (4 waves as 2x2). XOR-swizzled LDS.
// A swizzle on 8B granules: g = c4 ^ ((row&7)<<1); B on 16B: c ^ (col&7).

template<int BN, typename OutT>
__global__ __launch_bounds__(256, 2) void k_gemm_split(const float* __restrict__ A,
                                                       const _Float16* __restrict__ Bth,
                                                       const _Float16* __restrict__ Btl,
                                                       OutT* __restrict__ C,
                                                       int n, int m) {
    constexpr int NI  = BN / 32;      // 16-col frags per wave
    constexpr int BIT = BN / 32;      // B staging iterations (16B chunks)
    __shared__ _Float16 Ash[128 * 64];
    __shared__ _Float16 Asl[128 * 64];
    __shared__ _Float16 Bsh[BN * 64];
    __shared__ _Float16 Bsl[BN * 64];
    int tid = threadIdx.x;
    int wv = tid >> 6, lane = tid & 63;
    int wr = wv >> 1, wc = wv & 1;
    int r0 = blockIdx.y * 128;
    int c0 = blockIdx.x * BN;

    float4 areg[8];
    f16x8 bregh[BIT], bregl[BIT];
    f32x4 acc[4][NI];
    #pragma unroll
    for (int i = 0; i < 4; i++)
        #pragma unroll
        for (int j = 0; j < NI; j++)
            acc[i][j] = (f32x4){0.f, 0.f, 0.f, 0.f};

    auto aload = [&](int kt) {
        #pragma unroll
        for (int i = 0; i < 8; ++i) {            // A: 128x64 fp32, float4 chunks
            int q = tid + 256 * i;
            int row = q >> 4, c4 = q & 15;
            int gr = r0 + row; if (gr >= n) gr = n - 1;
            areg[i] = *(const float4*)(A + (size_t)gr * 512 + kt * 64 + c4 * 4);
        }
        #pragma unroll
        for (int i = 0; i < BIT; ++i) {          // B hi/lo: BNx64 fp16, 16B chunks
            int q = tid + 256 * i;
            int col = q >> 3, c = q & 7;
            size_t off = (size_t)(c0 + col) * 512 + kt * 64 + c * 8;
            bregh[i] = *(const f16x8*)(Bth + off);
            bregl[i] = *(const f16x8*)(Btl + off);
        }
    };

    aload(0);
    for (int kt = 0; kt < 8; ++kt) {
        __syncthreads();   // previous tile's reads done
        #pragma unroll
        for (int i = 0; i < 8; ++i) {
            int q = tid + 256 * i;
            int row = q >> 4, c4 = q & 15;
            int g = c4 ^ ((row & 7) << 1);       // 8B-granule swizzle
            float4 a = areg[i];
            _Float16 hx = (_Float16)a.x, hy = (_Float16)a.y;
            _Float16 hz = (_Float16)a.z, hw = (_Float16)a.w;
            f16x4 h = { hx, hy, hz, hw };
            f16x4 l = { (_Float16)(a.x - (float)hx), (_Float16)(a.y - (float)hy),
                        (_Float16)(a.z - (float)hz), (_Float16)(a.w - (float)hw) };
            *(f16x4*)&Ash[row * 64 + g * 4] = h;
            *(f16x4*)&Asl[row * 64 + g * 4] = l;
        }
        #pragma unroll
        for (int i = 0; i < BIT; ++i) {
            int q = tid + 256 * i;
            int col = q >> 3, c = q & 7;
            int idx = col * 64 + ((c ^ (col & 7)) * 8);
            *(f16x8*)&Bsh[idx] = bregh[i];
            *(f16x8*)&Bsl[idx] = bregl[i];
        }
        __syncthreads();
        if (kt < 7) aload(kt + 1);   // prefetch rides under the MFMAs
        #pragma unroll
        for (int ks = 0; ks < 2; ++ks) {
            f16x8 afh[4], afl[4], bfh[NI], bfl[NI];
            int cch = ks * 4 + (lane >> 4);      // 16B granule index (0..7)
            #pragma unroll
            for (int mi = 0; mi < 4; ++mi) {
                int row = wr * 64 + mi * 16 + (lane & 15);
                int idx = row * 64 + (((cch * 2) ^ ((row & 7) << 1)) * 4);
                afh[mi] = *(const f16x8*)&Ash[idx];
                afl[mi] = *(const f16x8*)&Asl[idx];
            }
            #pragma unroll
            for (int ni = 0; ni < NI; ++ni) {
                int col = wc * (BN / 2) + ni * 16 + (lane & 15);
                int idx = col * 64 + ((cch ^ (col & 7)) * 8);
                bfh[ni] = *(const f16x8*)&Bsh[idx];
                bfl[ni] = *(const f16x8*)&Bsl[idx];
            }
            #pragma unroll
            for (int mi = 0; mi < 4; ++mi)
                #pragma unroll
                for (int ni = 0; ni < NI; ++ni) {
                    acc[mi][ni] = __builtin_amdgcn_mfma_f32_16x16x32_f16(
                        afh[mi], bfl[ni], acc[mi][ni], 0, 0, 0);
                    acc[mi][ni] = __builtin_amdgcn_mfma_f32_16x16x32_f16(
                        afl[mi], bfh[ni], acc[mi][ni], 0, 0, 0);
                    acc[mi][ni] = __builtin_amdgcn_mfma_f32_16x16x32_f16(
                        afh[mi], bfh[ni], acc[mi][ni], 0, 0, 0);
                }
        }
    }

    // epilogue: C/D layout col=lane&15, row=(lane>>4)*4+j
    #pragma unroll
    for (int mi = 0; mi < 4; ++mi) {
        #pragma unroll
        for (int j = 0; j < 4; ++j) {
            int gr = r0 + wr * 64 + mi * 16 + (lane >> 4) * 4 + j;
            if (gr < n) {
                #pragma unroll
                for (int ni = 0; ni < NI; ++ni) {
                    int gc = c0 + wc * (BN / 2) + ni * 16 + (lane & 15);
                    C[(size_t)gr * m + gc] = (OutT)acc[mi][ni][j];
                }
            }
        }
    }
}

// ---------------- SpMM K=512: fp16 gather -> fp32 out (+bias, +relu) ----------------

__global__ __launch_bounds__(64) void k_spmm512_h2f(const int* __restrict__ rowp,
                                                    const int* __restrict__ ecol,
                                                    const float* __restrict__ ew,
                                                    const _Float16* __restrict__ H,
                                                    const float* __restrict__ bias,
                                                    float* __restrict__ out,
                                                    int relu) {
    int row = blockIdx.x;
    int t = threadIdx.x;                 // 64 threads, each owns 8 cols (f16x8)
    int s0 = rowp[row], s1 = rowp[row + 1];
    const f16x8* H8 = (const f16x8*)H;   // row stride 64 vectors
    float a0 = 0.f, a1 = 0.f, a2 = 0.f, a3 = 0.f;
    float a4 = 0.f, a5 = 0.f, a6 = 0.f, a7 = 0.f;
    __shared__ int   lc[64];
    __shared__ float lw[64];
    for (int base = s0; base < s1; base += 64) {
        int nn = s1 - base; if (nn > 64) nn = 64;
        __syncthreads();
        if (t < nn) { lc[t] = ecol[base + t]; lw[t] = ew[base + t]; }
        __syncthreads();
        int e = 0;
        for (; e + 4 <= nn; e += 4) {
            f16x8 h0 = H8[(size_t)lc[e]     * 64 + t]; float w0 = lw[e];
            f16x8 h1 = H8[(size_t)lc[e + 1] * 64 + t]; float w1 = lw[e + 1];
            f16x8 h2 = H8[(size_t)lc[e + 2] * 64 + t]; float w2 = lw[e + 2];
            f16x8 h3 = H8[(size_t)lc[e + 3] * 64 + t]; float w3 = lw[e + 3];
            a0 += w0 * (float)h0[0] + w1 * (float)h1[0] + w2 * (float)h2[0] + w3 * (float)h3[0];
            a1 += w0 * (float)h0[1] + w1 * (float)h1[1] + w2 * (float)h2[1] + w3 * (float)h3[1];
            a2 += w0 * (float)h0[2] + w1 * (float)h1[2] + w2 * (float)h2[2] + w3 * (float)h3[2];
            a3 += w0 * (float)h0[3] + w1 * (float)h1[3] + w2 * (float)h2[3] + w3 * (float)h3[3];
            a4 += w0 * (float)h0[4] + w1 * (float)h1[4] + w2 * (float)h2[4] + w3 * (float)h3[4];
            a5 += w0 * (float)h0[5] + w1 * (float)h1[5] + w2 * (float)h2[5] + w3 * (float)h3[5];
            a6 += w0 * (float)h0[6] + w1 * (float)h1[6] + w2 * (float)h2[6] + w3 * (float)h3[6];
            a7 += w0 * (float)h0[7] + w1 * (float)h1[7] + w2 * (float)h2[7] + w3 * (float)h3[7];
        }
        for (; e < nn; ++e) {
            f16x8 h = H8[(size_t)lc[e] * 64 + t]; float w = lw[e];
            a0 += w * (float)h[0]; a1 += w * (float)h[1];
            a2 += w * (float)h[2]; a3 += w * (float)h[3];
            a4 += w * (float)h[4]; a5 += w * (float)h[5];
            a6 += w * (float)h[6]; a7 += w * (float)h[7];
        }
    }
    const float4* b4 = (const float4*)bias;
    float4 blo = b4[t * 2], bhi = b4[t * 2 + 1];
    a0 += blo.x; a1 += blo.y; a2 += blo.z; a3 += blo.w;
    a4 += bhi.x; a5 += bhi.y; a6 += bhi.z; a7 += bhi.w;
    if (relu) {
        a0 = fmaxf(a0, 0.f); a1 = fmaxf(a1, 0.f); a2 = fmaxf(a2, 0.f); a3 = fmaxf(a3, 0.f);
        a4 = fmaxf(a4, 0.f); a5 = fmaxf(a5, 0.f); a6 = fmaxf(a6, 0.f); a7 = fmaxf(a7, 0.f);
    }
    float4 o1 = { a0, a1, a2, a3 };
    float4 o2 = { a4, a5, a6, a7 };
    float4* op = (float4*)(out + (size_t)row * 512);
    op[t * 2]     = o1;
    op[t * 2 + 1] = o2;
}

// ---------------- SpMM K=64 fp32 + bias + softmax, one wave per dst row ----------------

__global__ __launch_bounds__(256) void k_spmm64_softmax(const int* __restrict__ rowp,
                                                        const int* __restrict__ ecol,
                                                        const float* __restrict__ ew,
                                                        const float* __restrict__ H,
                                                        const float* __restrict__ bias,
                                                        float* __restrict__ out, int n) {
    int wid  = threadIdx.x >> 6;
    int lane = threadIdx.x & 63;
    int row  = blockIdx.x * 4 + wid;
    if (row >= n) return;
    int s0 = rowp[row], s1 = rowp[row + 1];
    float acc = 0.f;
    int e = s0;
    for (; e + 2 <= s1; e += 2) {
        int   c0 = ecol[e], c1 = ecol[e + 1];
        float w0 = ew[e],   w1 = ew[e + 1];
        acc += w0 * H[(size_t)c0 * 64 + lane] + w1 * H[(size_t)c1 * 64 + lane];
    }
    if (e < s1) acc += ew[e] * H[(size_t)ecol[e] * 64 + lane];
    acc += bias[lane];
    float m = acc;
    for (int d = 32; d > 0; d >>= 1) m = fmaxf(m, __shfl_xor(m, d));
    float p = __expf(acc - m);
    float s = p;
    for (int d = 32; d > 0; d >>= 1) s += __shfl_xor(s, d);
    out[(size_t)row * 64 + lane] = p / s;
}

// ---------------- launch ----------------

extern "C" void kernel_launch(void* const* d_in, const int* in_sizes, int n_in,
                              void* d_out, int out_size, void* d_ws, size_t ws_size,
                              hipStream_t stream) {
    const float* X    = (const float*)d_in[0];
    const int*   esrc = (const int*)d_in[1];
    const int*   edst = (const int*)d_in[2];
    const float* ewin = (const float*)d_in[3];
    const float* W0   = (const float*)d_in[4];
    const float* b0   = (const float*)d_in[5];
    const float* W1   = (const float*)d_in[6];
    const float* b1   = (const float*)d_in[7];
    const float* W2   = (const float*)d_in[8];
    const float* b2   = (const float*)d_in[9];
    float* out = (float*)d_out;

    const int N = GN;
    const int E = GE;

    uint8_t* p = (uint8_t*)d_ws;
    auto alloc = [&](size_t bytes) -> void* {
        void* r = (void*)p;
        p += (bytes + 255) & ~(size_t)255;
        return r;
    };
    _Float16* bufM  = (_Float16*)alloc((size_t)N * 512 * 2);   // GEMM out (fp16, gather table)
    float*    bufG  = (float*)alloc((size_t)N * 512 * 4);      // spmm out (fp32, next A)
    float*    bufC3 = (float*)alloc((size_t)N * 64 * 4);       // layer-3 logits pre-agg (fp32)
    _Float16* W0th  = (_Float16*)alloc((size_t)512 * 512 * 2);
    _Float16* W0tl  = (_Float16*)alloc((size_t)512 * 512 * 2);
    _Float16* W1th  = (_Float16*)alloc((size_t)512 * 512 * 2);
    _Float16* W1tl  = (_Float16*)alloc((size_t)512 * 512 * 2);
    _Float16* W2th  = (_Float16*)alloc((size_t)64 * 512 * 2);
    _Float16* W2tl  = (_Float16*)alloc((size_t)64 * 512 * 2);
    int*   cnt     = (int*)alloc((size_t)N * 4);
    int*   row_ptr = (int*)alloc((size_t)(N + 1) * 4);
    int*   cursor  = (int*)alloc((size_t)N * 4);
    int*   ecol    = (int*)alloc((size_t)E * 4);
    float* ewv     = (float*)alloc((size_t)E * 4);
    int*   bsum    = (int*)alloc(1024 * 4);
    int*   boff    = (int*)alloc(1024 * 4);

    // CSR by dst
    int nch = (N + 511) / 512;
    k_zero<<<(N + 255) / 256, 256, 0, stream>>>(cnt, N);
    k_hist<<<2048, 256, 0, stream>>>(edst, cnt, E);
    k_chunksum<<<nch, 256, 0, stream>>>(cnt, bsum, N);
    k_scanb<<<1, 64, 0, stream>>>(bsum, boff, nch, row_ptr, N);
    k_scanw<<<nch, 512, 0, stream>>>(cnt, boff, row_ptr, cursor, N);
    k_scatter<<<2048, 256, 0, stream>>>(esrc, edst, ewin, cursor, ecol, ewv, E);

    // weight split-transpose (hi/lo fp16)
    k_transp_split<<<dim3(16, 16), dim3(32, 8), 0, stream>>>(W0, W0th, W0tl, 512, 512);
    k_transp_split<<<dim3(16, 16), dim3(32, 8), 0, stream>>>(W1, W1th, W1tl, 512, 512);
    k_transp_split<<<dim3(2, 16),  dim3(32, 8), 0, stream>>>(W2, W2th, W2tl, 512, 64);

    int gy = (N + 127) / 128;
    // layer 1: M = X @ W0 (split fp16 MFMA, fp32-accurate), H = relu(spmm(M) + b0)
    k_gemm_split<128, _Float16><<<dim3(4, gy), 256, 0, stream>>>(X, W0th, W0tl, bufM, N, 512);
    k_spmm512_h2f<<<N, 64, 0, stream>>>(row_ptr, ecol, ewv, bufM, b0, bufG, 1);
    // layer 2
    k_gemm_split<128, _Float16><<<dim3(4, gy), 256, 0, stream>>>(bufG, W1th, W1tl, bufM, N, 512);
    k_spmm512_h2f<<<N, 64, 0, stream>>>(row_ptr, ecol, ewv, bufM, b1, bufG, 1);
    // layer 3 + softmax (fp32 logits end-to-end)
    k_gemm_split<64, float><<<dim3(1, gy), 256, 0, stream>>>(bufG, W2th, W2tl, bufC3, N, 64);
    k_spmm64_softmax<<<(N + 3) / 4, 256, 0, stream>>>(row_ptr, ecol, ewv, bufC3, b2, out, N);
}

// Round 6
// 1895.899 us; speedup vs baseline: 1.9025x; 1.0070x over previous
//
#include <hip/hip_runtime.h>
#include <hip/hip_bf16.h>
#include <cstdint>
#include <cstddef>

#define GN 100000
#define GE 3200000

typedef __attribute__((ext_vector_type(8))) _Float16 f16x8;
typedef __attribute__((ext_vector_type(4))) _Float16 f16x4;
typedef __attribute__((ext_vector_type(4))) float f32x4;

// ---------------- CSR build ----------------

__global__ void k_zero(int* __restrict__ p, int n) {
    int i = blockIdx.x * blockDim.x + threadIdx.x;
    if (i < n) p[i] = 0;
}

__global__ void k_hist(const int* __restrict__ dst, int* __restrict__ cnt, int e) {
    for (int i = blockIdx.x * blockDim.x + threadIdx.x; i < e; i += gridDim.x * blockDim.x)
        atomicAdd(&cnt[dst[i]], 1);
}

__global__ void k_chunksum(const int* __restrict__ cnt, int* __restrict__ bsum, int n) {
    __shared__ int s[256];
    int b = blockIdx.x, t = threadIdx.x;
    int i0 = b * 512;
    int v = 0;
    int i1 = i0 + t;        if (i1 < n) v += cnt[i1];
    int i2 = i0 + 256 + t;  if (i2 < n) v += cnt[i2];
    s[t] = v; __syncthreads();
    for (int d = 128; d > 0; d >>= 1) {
        if (t < d) s[t] += s[t + d];
        __syncthreads();
    }
    if (t == 0) bsum[b] = s[0];
}

__global__ void k_scanb(const int* __restrict__ bsum, int* __restrict__ boff, int nb,
                        int* __restrict__ row_ptr, int n) {
    if (threadIdx.x == 0 && blockIdx.x == 0) {
        int acc = 0;
        for (int b = 0; b < nb; b++) { boff[b] = acc; acc += bsum[b]; }
        row_ptr[n] = acc;
    }
}

__global__ void k_scanw(const int* __restrict__ cnt, const int* __restrict__ boff,
                        int* __restrict__ row_ptr, int* __restrict__ cursor, int n) {
    __shared__ int s[512];
    int b = blockIdx.x, t = threadIdx.x;
    int i = b * 512 + t;
    int x = (i < n) ? cnt[i] : 0;
    s[t] = x; __syncthreads();
    for (int d = 1; d < 512; d <<= 1) {
        int v = (t >= d) ? s[t - d] : 0;
        __syncthreads();
        s[t] += v;
        __syncthreads();
    }
    int excl = s[t] - x + boff[b];
    if (i < n) { row_ptr[i] = excl; cursor[i] = excl; }
}

__global__ void k_scatter(const int* __restrict__ src, const int* __restrict__ dst,
                          const float* __restrict__ w, int* __restrict__ cursor,
                          int* __restrict__ ecol, float* __restrict__ ew, int e) {
    for (int i = blockIdx.x * blockDim.x + threadIdx.x; i < e; i += gridDim.x * blockDim.x) {
        int d = dst[i];
        int p = atomicAdd(&cursor[d], 1);
        ecol[p] = src[i];
        ew[p]   = w[i];
    }
}

// ---------------- W[K][M] fp32 -> split-transposed Wth/Wtl[M][K] fp16 ----------------

__global__ void k_transp_split(const float* __restrict__ W,
                               _Float16* __restrict__ Wth, _Float16* __restrict__ Wtl,
                               int K, int M) {
    __shared__ float tile[32][33];
    int bx = blockIdx.x * 32;  // M dim
    int by = blockIdx.y * 32;  // K dim
    int tx = threadIdx.x, ty = threadIdx.y;
    for (int i = ty; i < 32; i += 8)
        tile[i][tx] = W[(size_t)(by + i) * M + bx + tx];
    __syncthreads();
    for (int i = ty; i < 32; i += 8) {
        float w = tile[tx][i];
        _Float16 h = (_Float16)w;
        _Float16 l = (_Float16)(w - (float)h);
        Wth[(size_t)(bx + i) * K + by + tx] = h;
        Wtl[(size_t)(bx + i) * K + by + tx] = l;
    }
}

// ---------------- split fp16 MFMA GEMM: C[n x m] = A[n x 512] @ Bt^T ----------------
// A row-major fp32 [n][512] (split to hi/lo fp16 on the fly);
// Bth/Btl = W^T hi/lo, row-major fp16 [m][512]; C = OutT [n][m].
// acc = Ah*Bh + Al*Bh + Ah*Bl (fp32 acc) -> effective fp32-level precision.
// Tile 128 x BN, BK=64, 256 threads (4 waves as 2x2). XOR-swizzled LDS.

template<int BN, typename OutT>
__global__ __launch_bounds__(256, 2) void k_gemm_split(const float* __restrict__ A,
                                                       const _Float16* __restrict__ Bth,
                                                       const _Float16* __restrict__ Btl,
                                                       OutT* __restrict__ C,
                                                       int n, int m) {
    constexpr int NI  = BN / 32;      // 16-col frags per wave
    constexpr int BIT = BN / 32;      // B staging iterations (16B chunks)
    __shared__ _Float16 Ash[128 * 64];
    __shared__ _Float16 Asl[128 * 64];
    __shared__ _Float16 Bsh[BN * 64];
    __shared__ _Float16 Bsl[BN * 64];
    int tid = threadIdx.x;
    int wv = tid >> 6, lane = tid & 63;
    int wr = wv >> 1, wc = wv & 1;
    int r0 = blockIdx.y * 128;
    int c0 = blockIdx.x * BN;

    float4 areg[8];
    f16x8 bregh[BIT], bregl[BIT];
    f32x4 acc[4][NI];
    #pragma unroll
    for (int i = 0; i < 4; i++)
        #pragma unroll
        for (int j = 0; j < NI; j++)
            acc[i][j] = (f32x4){0.f, 0.f, 0.f, 0.f};

    auto aload = [&](int kt) {
        #pragma unroll
        for (int i = 0; i < 8; ++i) {            // A: 128x64 fp32, float4 chunks
            int q = tid + 256 * i;
            int row = q >> 4, c4 = q & 15;
            int gr = r0 + row; if (gr >= n) gr = n - 1;
            areg[i] = *(const float4*)(A + (size_t)gr * 512 + kt * 64 + c4 * 4);
        }
        #pragma unroll
        for (int i = 0; i < BIT; ++i) {          // B hi/lo: BNx64 fp16, 16B chunks
            int q = tid + 256 * i;
            int col = q >> 3, c = q & 7;
            size_t off = (size_t)(c0 + col) * 512 + kt * 64 + c * 8;
            bregh[i] = *(const f16x8*)(Bth + off);
            bregl[i] = *(const f16x8*)(Btl + off);
        }
    };

    aload(0);
    for (int kt = 0; kt < 8; ++kt) {
        __syncthreads();   // previous tile's reads done
        #pragma unroll
        for (int i = 0; i < 8; ++i) {
            int q = tid + 256 * i;
            int row = q >> 4, c4 = q & 15;
            int g = c4 ^ ((row & 7) << 1);       // 8B-granule swizzle
            float4 a = areg[i];
            _Float16 hx = (_Float16)a.x, hy = (_Float16)a.y;
            _Float16 hz = (_Float16)a.z, hw = (_Float16)a.w;
            f16x4 h = { hx, hy, hz, hw };
            f16x4 l = { (_Float16)(a.x - (float)hx), (_Float16)(a.y - (float)hy),
                        (_Float16)(a.z - (float)hz), (_Float16)(a.w - (float)hw) };
            *(f16x4*)&Ash[row * 64 + g * 4] = h;
            *(f16x4*)&Asl[row * 64 + g * 4] = l;
        }
        #pragma unroll
        for (int i = 0; i < BIT; ++i) {
            int q = tid + 256 * i;
            int col = q >> 3, c = q & 7;
            int idx = col * 64 + ((c ^ (col & 7)) * 8);
            *(f16x8*)&Bsh[idx] = bregh[i];
            *(f16x8*)&Bsl[idx] = bregl[i];
        }
        __syncthreads();
        if (kt < 7) aload(kt + 1);   // prefetch rides under the MFMAs
        #pragma unroll
        for (int ks = 0; ks < 2; ++ks) {
            f16x8 afh[4], afl[4], bfh[NI], bfl[NI];
            int cch = ks * 4 + (lane >> 4);      // 16B granule index (0..7)
            #pragma unroll
            for (int mi = 0; mi < 4; ++mi) {
                int row = wr * 64 + mi * 16 + (lane & 15);
                int idx = row * 64 + (((cch * 2) ^ ((row & 7) << 1)) * 4);
                afh[mi] = *(const f16x8*)&Ash[idx];
                afl[mi] = *(const f16x8*)&Asl[idx];
            }
            #pragma unroll
            for (int ni = 0; ni < NI; ++ni) {
                int col = wc * (BN / 2) + ni * 16 + (lane & 15);
                int idx = col * 64 + ((cch ^ (col & 7)) * 8);
                bfh[ni] = *(const f16x8*)&Bsh[idx];
                bfl[ni] = *(const f16x8*)&Bsl[idx];
            }
            #pragma unroll
            for (int mi = 0; mi < 4; ++mi)
                #pragma unroll
                for (int ni = 0; ni < NI; ++ni) {
                    acc[mi][ni] = __builtin_amdgcn_mfma_f32_16x16x32_f16(
                        afh[mi], bfl[ni], acc[mi][ni], 0, 0, 0);
                    acc[mi][ni] = __builtin_amdgcn_mfma_f32_16x16x32_f16(
                        afl[mi], bfh[ni], acc[mi][ni], 0, 0, 0);
                    acc[mi][ni] = __builtin_amdgcn_mfma_f32_16x16x32_f16(
                        afh[mi], bfh[ni], acc[mi][ni], 0, 0, 0);
                }
        }
    }

    // epilogue: C/D layout col=lane&15, row=(lane>>4)*4+j
    // (C here is the gather table M or bufC3 -> re-read soon, keep cached)
    #pragma unroll
    for (int mi = 0; mi < 4; ++mi) {
        #pragma unroll
        for (int j = 0; j < 4; ++j) {
            int gr = r0 + wr * 64 + mi * 16 + (lane >> 4) * 4 + j;
            if (gr < n) {
                #pragma unroll
                for (int ni = 0; ni < NI; ++ni) {
                    int gc = c0 + wc * (BN / 2) + ni * 16 + (lane & 15);
                    C[(size_t)gr * m + gc] = (OutT)acc[mi][ni][j];
                }
            }
        }
    }
}

// ---------------- SpMM K=512: fp16 gather -> fp32 out (+bias, +relu) ----------------
// NT stores on the 205 MB output stream + NT loads on the edge stream keep the
// 102 MB gather table L3-resident (anti-thrash).

__global__ __launch_bounds__(64) void k_spmm512_h2f(const int* __restrict__ rowp,
                                                    const int* __restrict__ ecol,
                                                    const float* __restrict__ ew,
                                                    const _Float16* __restrict__ H,
                                                    const float* __restrict__ bias,
                                                    float* __restrict__ out,
                                                    int relu) {
    int row = blockIdx.x;
    int t = threadIdx.x;                 // 64 threads, each owns 8 cols (f16x8)
    int s0 = rowp[row], s1 = rowp[row + 1];
    const f16x8* H8 = (const f16x8*)H;   // row stride 64 vectors
    float a0 = 0.f, a1 = 0.f, a2 = 0.f, a3 = 0.f;
    float a4 = 0.f, a5 = 0.f, a6 = 0.f, a7 = 0.f;
    __shared__ int   lc[64];
    __shared__ float lw[64];
    for (int base = s0; base < s1; base += 64) {
        int nn = s1 - base; if (nn > 64) nn = 64;
        __syncthreads();
        if (t < nn) {
            lc[t] = __builtin_nontemporal_load(ecol + base + t);
            lw[t] = __builtin_nontemporal_load(ew + base + t);
        }
        __syncthreads();
        int e = 0;
        for (; e + 4 <= nn; e += 4) {
            f16x8 h0 = H8[(size_t)lc[e]     * 64 + t]; float w0 = lw[e];
            f16x8 h1 = H8[(size_t)lc[e + 1] * 64 + t]; float w1 = lw[e + 1];
            f16x8 h2 = H8[(size_t)lc[e + 2] * 64 + t]; float w2 = lw[e + 2];
            f16x8 h3 = H8[(size_t)lc[e + 3] * 64 + t]; float w3 = lw[e + 3];
            a0 += w0 * (float)h0[0] + w1 * (float)h1[0] + w2 * (float)h2[0] + w3 * (float)h3[0];
            a1 += w0 * (float)h0[1] + w1 * (float)h1[1] + w2 * (float)h2[1] + w3 * (float)h3[1];
            a2 += w0 * (float)h0[2] + w1 * (float)h1[2] + w2 * (float)h2[2] + w3 * (float)h3[2];
            a3 += w0 * (float)h0[3] + w1 * (float)h1[3] + w2 * (float)h2[3] + w3 * (float)h3[3];
            a4 += w0 * (float)h0[4] + w1 * (float)h1[4] + w2 * (float)h2[4] + w3 * (float)h3[4];
            a5 += w0 * (float)h0[5] + w1 * (float)h1[5] + w2 * (float)h2[5] + w3 * (float)h3[5];
            a6 += w0 * (float)h0[6] + w1 * (float)h1[6] + w2 * (float)h2[6] + w3 * (float)h3[6];
            a7 += w0 * (float)h0[7] + w1 * (float)h1[7] + w2 * (float)h2[7] + w3 * (float)h3[7];
        }
        for (; e < nn; ++e) {
            f16x8 h = H8[(size_t)lc[e] * 64 + t]; float w = lw[e];
            a0 += w * (float)h[0]; a1 += w * (float)h[1];
            a2 += w * (float)h[2]; a3 += w * (float)h[3];
            a4 += w * (float)h[4]; a5 += w * (float)h[5];
            a6 += w * (float)h[6]; a7 += w * (float)h[7];
        }
    }
    const float4* b4 = (const float4*)bias;
    float4 blo = b4[t * 2], bhi = b4[t * 2 + 1];
    a0 += blo.x; a1 += blo.y; a2 += blo.z; a3 += blo.w;
    a4 += bhi.x; a5 += bhi.y; a6 += bhi.z; a7 += bhi.w;
    if (relu) {
        a0 = fmaxf(a0, 0.f); a1 = fmaxf(a1, 0.f); a2 = fmaxf(a2, 0.f); a3 = fmaxf(a3, 0.f);
        a4 = fmaxf(a4, 0.f); a5 = fmaxf(a5, 0.f); a6 = fmaxf(a6, 0.f); a7 = fmaxf(a7, 0.f);
    }
    f32x4 o1 = { a0, a1, a2, a3 };
    f32x4 o2 = { a4, a5, a6, a7 };
    f32x4* op = (f32x4*)(out + (size_t)row * 512);
    __builtin_nontemporal_store(o1, op + t * 2);
    __builtin_nontemporal_store(o2, op + t * 2 + 1);
}

// ---------------- SpMM K=64 fp32 + bias + softmax, one wave per dst row ----------------

__global__ __launch_bounds__(256) void k_spmm64_softmax(const int* __restrict__ rowp,
                                                        const int* __restrict__ ecol,
                                                        const float* __restrict__ ew,
                                                        const float* __restrict__ H,
                                                        const float* __restrict__ bias,
                                                        float* __restrict__ out, int n) {
    int wid  = threadIdx.x >> 6;
    int lane = threadIdx.x & 63;
    int row  = blockIdx.x * 4 + wid;
    if (row >= n) return;
    int s0 = rowp[row], s1 = rowp[row + 1];
    float acc = 0.f;
    int e = s0;
    for (; e + 2 <= s1; e += 2) {
        int   c0 = ecol[e], c1 = ecol[e + 1];
        float w0 = ew[e],   w1 = ew[e + 1];
        acc += w0 * H[(size_t)c0 * 64 + lane] + w1 * H[(size_t)c1 * 64 + lane];
    }
    if (e < s1) acc += ew[e] * H[(size_t)ecol[e] * 64 + lane];
    acc += bias[lane];
    float m = acc;
    for (int d = 32; d > 0; d >>= 1) m = fmaxf(m, __shfl_xor(m, d));
    float p = __expf(acc - m);
    float s = p;
    for (int d = 32; d > 0; d >>= 1) s += __shfl_xor(s, d);
    __builtin_nontemporal_store(p / s, out + (size_t)row * 64 + lane);
}

// ---------------- launch ----------------

extern "C" void kernel_launch(void* const* d_in, const int* in_sizes, int n_in,
                              void* d_out, int out_size, void* d_ws, size_t ws_size,
                              hipStream_t stream) {
    const float* X    = (const float*)d_in[0];
    const int*   esrc = (const int*)d_in[1];
    const int*   edst = (const int*)d_in[2];
    const float* ewin = (const float*)d_in[3];
    const float* W0   = (const float*)d_in[4];
    const float* b0   = (const float*)d_in[5];
    const float* W1   = (const float*)d_in[6];
    const float* b1   = (const float*)d_in[7];
    const float* W2   = (const float*)d_in[8];
    const float* b2   = (const float*)d_in[9];
    float* out = (float*)d_out;

    const int N = GN;
    const int E = GE;

    uint8_t* p = (uint8_t*)d_ws;
    auto alloc = [&](size_t bytes) -> void* {
        void* r = (void*)p;
        p += (bytes + 255) & ~(size_t)255;
        return r;
    };
    _Float16* bufM  = (_Float16*)alloc((size_t)N * 512 * 2);   // GEMM out (fp16, gather table)
    float*    bufG  = (float*)alloc((size_t)N * 512 * 4);      // spmm out (fp32, next A)
    float*    bufC3 = (float*)alloc((size_t)N * 64 * 4);       // layer-3 logits pre-agg (fp32)
    _Float16* W0th  = (_Float16*)alloc((size_t)512 * 512 * 2);
    _Float16* W0tl  = (_Float16*)alloc((size_t)512 * 512 * 2);
    _Float16* W1th  = (_Float16*)alloc((size_t)512 * 512 * 2);
    _Float16* W1tl  = (_Float16*)alloc((size_t)512 * 512 * 2);
    _Float16* W2th  = (_Float16*)alloc((size_t)64 * 512 * 2);
    _Float16* W2tl  = (_Float16*)alloc((size_t)64 * 512 * 2);
    int*   cnt     = (int*)alloc((size_t)N * 4);
    int*   row_ptr = (int*)alloc((size_t)(N + 1) * 4);
    int*   cursor  = (int*)alloc((size_t)N * 4);
    int*   ecol    = (int*)alloc((size_t)E * 4);
    float* ewv     = (float*)alloc((size_t)E * 4);
    int*   bsum    = (int*)alloc(1024 * 4);
    int*   boff    = (int*)alloc(1024 * 4);

    // CSR by dst
    int nch = (N + 511) / 512;
    k_zero<<<(N + 255) / 256, 256, 0, stream>>>(cnt, N);
    k_hist<<<2048, 256, 0, stream>>>(edst, cnt, E);
    k_chunksum<<<nch, 256, 0, stream>>>(cnt, bsum, N);
    k_scanb<<<1, 64, 0, stream>>>(bsum, boff, nch, row_ptr, N);
    k_scanw<<<nch, 512, 0, stream>>>(cnt, boff, row_ptr, cursor, N);
    k_scatter<<<2048, 256, 0, stream>>>(esrc, edst, ewin, cursor, ecol, ewv, E);

    // weight split-transpose (hi/lo fp16)
    k_transp_split<<<dim3(16, 16), dim3(32, 8), 0, stream>>>(W0, W0th, W0tl, 512, 512);
    k_transp_split<<<dim3(16, 16), dim3(32, 8), 0, stream>>>(W1, W1th, W1tl, 512, 512);
    k_transp_split<<<dim3(2, 16),  dim3(32, 8), 0, stream>>>(W2, W2th, W2tl, 512, 64);

    int gy = (N + 127) / 128;
    // layer 1: M = X @ W0 (split fp16 MFMA, fp32-accurate), H = relu(spmm(M) + b0)
    k_gemm_split<128, _Float16><<<dim3(4, gy), 256, 0, stream>>>(X, W0th, W0tl, bufM, N, 512);
    k_spmm512_h2f<<<N, 64, 0, stream>>>(row_ptr, ecol, ewv, bufM, b0, bufG, 1);
    // layer 2
    k_gemm_split<128, _Float16><<<dim3(4, gy), 256, 0, stream>>>(bufG, W1th, W1tl, bufM, N, 512);
    k_spmm512_h2f<<<N, 64, 0, stream>>>(row_ptr, ecol, ewv, bufM, b1, bufG, 1);
    // layer 3 + softmax (fp32 logits end-to-end)
    k_gemm_split<64, float><<<dim3(1, gy), 256, 0, stream>>>(bufG, W2th, W2tl, bufC3, N, 64);
    k_spmm64_softmax<<<(N + 3) / 4, 256, 0, stream>>>(row_ptr, ecol, ewv, bufC3, b2, out, N);
}

// Round 7
// 1708.751 us; speedup vs baseline: 2.1109x; 1.1095x over previous
//
#include <hip/hip_runtime.h>
#include <hip/hip_bf16.h>
#include <cstdint>
#include <cstddef>

#define GN 100000
#define GE 3200000

typedef __attribute__((ext_vector_type(8))) _Float16 f16x8;
typedef __attribute__((ext_vector_type(4))) _Float16 f16x4;
typedef __attribute__((ext_vector_type(4))) float f32x4;

// ---------------- CSR build ----------------

__global__ void k_zero(int* __restrict__ p, int n) {
    int i = blockIdx.x * blockDim.x + threadIdx.x;
    if (i < n) p[i] = 0;
}

__global__ void k_hist(const int* __restrict__ dst, int* __restrict__ cnt, int e) {
    for (int i = blockIdx.x * blockDim.x + threadIdx.x; i < e; i += gridDim.x * blockDim.x)
        atomicAdd(&cnt[dst[i]], 1);
}

__global__ void k_chunksum(const int* __restrict__ cnt, int* __restrict__ bsum, int n) {
    __shared__ int s[256];
    int b = blockIdx.x, t = threadIdx.x;
    int i0 = b * 512;
    int v = 0;
    int i1 = i0 + t;        if (i1 < n) v += cnt[i1];
    int i2 = i0 + 256 + t;  if (i2 < n) v += cnt[i2];
    s[t] = v; __syncthreads();
    for (int d = 128; d > 0; d >>= 1) {
        if (t < d) s[t] += s[t + d];
        __syncthreads();
    }
    if (t == 0) bsum[b] = s[0];
}

__global__ void k_scanb(const int* __restrict__ bsum, int* __restrict__ boff, int nb,
                        int* __restrict__ row_ptr, int n) {
    if (threadIdx.x == 0 && blockIdx.x == 0) {
        int acc = 0;
        for (int b = 0; b < nb; b++) { boff[b] = acc; acc += bsum[b]; }
        row_ptr[n] = acc;
    }
}

__global__ void k_scanw(const int* __restrict__ cnt, const int* __restrict__ boff,
                        int* __restrict__ row_ptr, int* __restrict__ cursor, int n) {
    __shared__ int s[512];
    int b = blockIdx.x, t = threadIdx.x;
    int i = b * 512 + t;
    int x = (i < n) ? cnt[i] : 0;
    s[t] = x; __syncthreads();
    for (int d = 1; d < 512; d <<= 1) {
        int v = (t >= d) ? s[t - d] : 0;
        __syncthreads();
        s[t] += v;
        __syncthreads();
    }
    int excl = s[t] - x + boff[b];
    if (i < n) { row_ptr[i] = excl; cursor[i] = excl; }
}

__global__ void k_scatter(const int* __restrict__ src, const int* __restrict__ dst,
                          const float* __restrict__ w, int* __restrict__ cursor,
                          int* __restrict__ ecol, float* __restrict__ ew, int e) {
    for (int i = blockIdx.x * blockDim.x + threadIdx.x; i < e; i += gridDim.x * blockDim.x) {
        int d = dst[i];
        int p = atomicAdd(&cursor[d], 1);
        ecol[p] = src[i];
        ew[p]   = w[i];
    }
}

// ---------------- W[K][M] fp32 -> split-transposed Wth/Wtl[M][K] fp16 ----------------

__global__ void k_transp_split(const float* __restrict__ W,
                               _Float16* __restrict__ Wth, _Float16* __restrict__ Wtl,
                               int K, int M) {
    __shared__ float tile[32][33];
    int bx = blockIdx.x * 32;  // M dim
    int by = blockIdx.y * 32;  // K dim
    int tx = threadIdx.x, ty = threadIdx.y;
    for (int i = ty; i < 32; i += 8)
        tile[i][tx] = W[(size_t)(by + i) * M + bx + tx];
    __syncthreads();
    for (int i = ty; i < 32; i += 8) {
        float w = tile[tx][i];
        _Float16 h = (_Float16)w;
        _Float16 l = (_Float16)(w - (float)h);
        Wth[(size_t)(bx + i) * K + by + tx] = h;
        Wtl[(size_t)(bx + i) * K + by + tx] = l;
    }
}

// ---------------- split fp16 MFMA GEMM (fp32 A): C = A @ Bt^T ----------------
// Layer-1 only: A row-major fp32 [n][512] split hi/lo on the fly (X never rounded).
// acc = Ah*Bh + Al*Bh + Ah*Bl.  Tile 128 x BN, BK=64, 256 thr. XOR-swizzled LDS.

template<int BN, typename OutT>
__global__ __launch_bounds__(256, 2) void k_gemm_split(const float* __restrict__ A,
                                                       const _Float16* __restrict__ Bth,
                                                       const _Float16* __restrict__ Btl,
                                                       OutT* __restrict__ C,
                                                       int n, int m) {
    constexpr int NI  = BN / 32;
    constexpr int BIT = BN / 32;
    __shared__ _Float16 Ash[128 * 64];
    __shared__ _Float16 Asl[128 * 64];
    __shared__ _Float16 Bsh[BN * 64];
    __shared__ _Float16 Bsl[BN * 64];
    int tid = threadIdx.x;
    int wv = tid >> 6, lane = tid & 63;
    int wr = wv >> 1, wc = wv & 1;
    int r0 = blockIdx.y * 128;
    int c0 = blockIdx.x * BN;

    float4 areg[8];
    f16x8 bregh[BIT], bregl[BIT];
    f32x4 acc[4][NI];
    #pragma unroll
    for (int i = 0; i < 4; i++)
        #pragma unroll
        for (int j = 0; j < NI; j++)
            acc[i][j] = (f32x4){0.f, 0.f, 0.f, 0.f};

    auto aload = [&](int kt) {
        #pragma unroll
        for (int i = 0; i < 8; ++i) {
            int q = tid + 256 * i;
            int row = q >> 4, c4 = q & 15;
            int gr = r0 + row; if (gr >= n) gr = n - 1;
            areg[i] = *(const float4*)(A + (size_t)gr * 512 + kt * 64 + c4 * 4);
        }
        #pragma unroll
        for (int i = 0; i < BIT; ++i) {
            int q = tid + 256 * i;
            int col = q >> 3, c = q & 7;
            size_t off = (size_t)(c0 + col) * 512 + kt * 64 + c * 8;
            bregh[i] = *(const f16x8*)(Bth + off);
            bregl[i] = *(const f16x8*)(Btl + off);
        }
    };

    aload(0);
    for (int kt = 0; kt < 8; ++kt) {
        __syncthreads();
        #pragma unroll
        for (int i = 0; i < 8; ++i) {
            int q = tid + 256 * i;
            int row = q >> 4, c4 = q & 15;
            int g = c4 ^ ((row & 7) << 1);
            float4 a = areg[i];
            _Float16 hx = (_Float16)a.x, hy = (_Float16)a.y;
            _Float16 hz = (_Float16)a.z, hw = (_Float16)a.w;
            f16x4 h = { hx, hy, hz, hw };
            f16x4 l = { (_Float16)(a.x - (float)hx), (_Float16)(a.y - (float)hy),
                        (_Float16)(a.z - (float)hz), (_Float16)(a.w - (float)hw) };
            *(f16x4*)&Ash[row * 64 + g * 4] = h;
            *(f16x4*)&Asl[row * 64 + g * 4] = l;
        }
        #pragma unroll
        for (int i = 0; i < BIT; ++i) {
            int q = tid + 256 * i;
            int col = q >> 3, c = q & 7;
            int idx = col * 64 + ((c ^ (col & 7)) * 8);
            *(f16x8*)&Bsh[idx] = bregh[i];
            *(f16x8*)&Bsl[idx] = bregl[i];
        }
        __syncthreads();
        if (kt < 7) aload(kt + 1);
        #pragma unroll
        for (int ks = 0; ks < 2; ++ks) {
            f16x8 afh[4], afl[4], bfh[NI], bfl[NI];
            int cch = ks * 4 + (lane >> 4);
            #pragma unroll
            for (int mi = 0; mi < 4; ++mi) {
                int row = wr * 64 + mi * 16 + (lane & 15);
                int idx = row * 64 + (((cch * 2) ^ ((row & 7) << 1)) * 4);
                afh[mi] = *(const f16x8*)&Ash[idx];
                afl[mi] = *(const f16x8*)&Asl[idx];
            }
            #pragma unroll
            for (int ni = 0; ni < NI; ++ni) {
                int col = wc * (BN / 2) + ni * 16 + (lane & 15);
                int idx = col * 64 + ((cch ^ (col & 7)) * 8);
                bfh[ni] = *(const f16x8*)&Bsh[idx];
                bfl[ni] = *(const f16x8*)&Bsl[idx];
            }
            #pragma unroll
            for (int mi = 0; mi < 4; ++mi)
                #pragma unroll
                for (int ni = 0; ni < NI; ++ni) {
                    acc[mi][ni] = __builtin_amdgcn_mfma_f32_16x16x32_f16(
                        afh[mi], bfl[ni], acc[mi][ni], 0, 0, 0);
                    acc[mi][ni] = __builtin_amdgcn_mfma_f32_16x16x32_f16(
                        afl[mi], bfh[ni], acc[mi][ni], 0, 0, 0);
                    acc[mi][ni] = __builtin_amdgcn_mfma_f32_16x16x32_f16(
                        afh[mi], bfh[ni], acc[mi][ni], 0, 0, 0);
                }
        }
    }

    #pragma unroll
    for (int mi = 0; mi < 4; ++mi) {
        #pragma unroll
        for (int j = 0; j < 4; ++j) {
            int gr = r0 + wr * 64 + mi * 16 + (lane >> 4) * 4 + j;
            if (gr < n) {
                #pragma unroll
                for (int ni = 0; ni < NI; ++ni) {
                    int gc = c0 + wc * (BN / 2) + ni * 16 + (lane & 15);
                    C[(size_t)gr * m + gc] = (OutT)acc[mi][ni][j];
                }
            }
        }
    }
}

// ---------------- fp16-A, split-W MFMA GEMM (layers 2,3) ----------------
// A row-major fp16 [n][512]; acc = Ah*Bh + Ah*Bl (2 MFMAs/pair; W keeps ~22-bit).

template<int BN, typename OutT>
__global__ __launch_bounds__(256, 2) void k_gemm_f16w2(const _Float16* __restrict__ A,
                                                       const _Float16* __restrict__ Bth,
                                                       const _Float16* __restrict__ Btl,
                                                       OutT* __restrict__ C,
                                                       int n, int m) {
    constexpr int NI  = BN / 32;
    constexpr int BIT = BN / 32;
    __shared__ _Float16 As[128 * 64];
    __shared__ _Float16 Bsh[BN * 64];
    __shared__ _Float16 Bsl[BN * 64];
    int tid = threadIdx.x;
    int wv = tid >> 6, lane = tid & 63;
    int wr = wv >> 1, wc = wv & 1;
    int r0 = blockIdx.y * 128;
    int c0 = blockIdx.x * BN;

    f16x8 areg[4], bregh[BIT], bregl[BIT];
    f32x4 acc[4][NI];
    #pragma unroll
    for (int i = 0; i < 4; i++)
        #pragma unroll
        for (int j = 0; j < NI; j++)
            acc[i][j] = (f32x4){0.f, 0.f, 0.f, 0.f};

    auto aload = [&](int kt) {
        #pragma unroll
        for (int i = 0; i < 4; ++i) {
            int q = tid + 256 * i;
            int row = q >> 3, c = q & 7;
            int gr = r0 + row; if (gr >= n) gr = n - 1;
            areg[i] = *(const f16x8*)(A + (size_t)gr * 512 + kt * 64 + c * 8);
        }
        #pragma unroll
        for (int i = 0; i < BIT; ++i) {
            int q = tid + 256 * i;
            int col = q >> 3, c = q & 7;
            size_t off = (size_t)(c0 + col) * 512 + kt * 64 + c * 8;
            bregh[i] = *(const f16x8*)(Bth + off);
            bregl[i] = *(const f16x8*)(Btl + off);
        }
    };

    aload(0);
    for (int kt = 0; kt < 8; ++kt) {
        __syncthreads();
        #pragma unroll
        for (int i = 0; i < 4; ++i) {
            int q = tid + 256 * i;
            int row = q >> 3, c = q & 7;
            *(f16x8*)&As[row * 64 + ((c ^ (row & 7)) * 8)] = areg[i];
        }
        #pragma unroll
        for (int i = 0; i < BIT; ++i) {
            int q = tid + 256 * i;
            int col = q >> 3, c = q & 7;
            int idx = col * 64 + ((c ^ (col & 7)) * 8);
            *(f16x8*)&Bsh[idx] = bregh[i];
            *(f16x8*)&Bsl[idx] = bregl[i];
        }
        __syncthreads();
        if (kt < 7) aload(kt + 1);
        #pragma unroll
        for (int ks = 0; ks < 2; ++ks) {
            f16x8 af[4], bfh[NI], bfl[NI];
            int cch = ks * 4 + (lane >> 4);
            #pragma unroll
            for (int mi = 0; mi < 4; ++mi) {
                int row = wr * 64 + mi * 16 + (lane & 15);
                af[mi] = *(const f16x8*)&As[row * 64 + ((cch ^ (row & 7)) * 8)];
            }
            #pragma unroll
            for (int ni = 0; ni < NI; ++ni) {
                int col = wc * (BN / 2) + ni * 16 + (lane & 15);
                int idx = col * 64 + ((cch ^ (col & 7)) * 8);
                bfh[ni] = *(const f16x8*)&Bsh[idx];
                bfl[ni] = *(const f16x8*)&Bsl[idx];
            }
            #pragma unroll
            for (int mi = 0; mi < 4; ++mi)
                #pragma unroll
                for (int ni = 0; ni < NI; ++ni) {
                    acc[mi][ni] = __builtin_amdgcn_mfma_f32_16x16x32_f16(
                        af[mi], bfl[ni], acc[mi][ni], 0, 0, 0);
                    acc[mi][ni] = __builtin_amdgcn_mfma_f32_16x16x32_f16(
                        af[mi], bfh[ni], acc[mi][ni], 0, 0, 0);
                }
        }
    }

    #pragma unroll
    for (int mi = 0; mi < 4; ++mi) {
        #pragma unroll
        for (int j = 0; j < 4; ++j) {
            int gr = r0 + wr * 64 + mi * 16 + (lane >> 4) * 4 + j;
            if (gr < n) {
                #pragma unroll
                for (int ni = 0; ni < NI; ++ni) {
                    int gc = c0 + wc * (BN / 2) + ni * 16 + (lane & 15);
                    C[(size_t)gr * m + gc] = (OutT)acc[mi][ni][j];
                }
            }
        }
    }
}

// ---------------- SpMM K=512: fp16 gather -> fp16 out (+bias, +relu), ILP 8 ----------------

__global__ __launch_bounds__(64) void k_spmm512_h2h(const int* __restrict__ rowp,
                                                    const int* __restrict__ ecol,
                                                    const float* __restrict__ ew,
                                                    const _Float16* __restrict__ H,
                                                    const float* __restrict__ bias,
                                                    _Float16* __restrict__ out,
                                                    int relu) {
    int row = blockIdx.x;
    int t = threadIdx.x;                 // 64 threads, each owns 8 cols (f16x8)
    int s0 = rowp[row], s1 = rowp[row + 1];
    const f16x8* H8 = (const f16x8*)H;   // row stride 64 vectors
    float a0 = 0.f, a1 = 0.f, a2 = 0.f, a3 = 0.f;
    float a4 = 0.f, a5 = 0.f, a6 = 0.f, a7 = 0.f;
    __shared__ int   lc[64];
    __shared__ float lw[64];
    for (int base = s0; base < s1; base += 64) {
        int nn = s1 - base; if (nn > 64) nn = 64;
        __syncthreads();
        if (t < nn) {
            lc[t] = __builtin_nontemporal_load(ecol + base + t);
            lw[t] = __builtin_nontemporal_load(ew + base + t);
        }
        __syncthreads();
        int e = 0;
        for (; e + 8 <= nn; e += 8) {      // 8 outstanding 1KB wave-gathers
            f16x8 h0 = H8[(size_t)lc[e]     * 64 + t];
            f16x8 h1 = H8[(size_t)lc[e + 1] * 64 + t];
            f16x8 h2 = H8[(size_t)lc[e + 2] * 64 + t];
            f16x8 h3 = H8[(size_t)lc[e + 3] * 64 + t];
            f16x8 h4 = H8[(size_t)lc[e + 4] * 64 + t];
            f16x8 h5 = H8[(size_t)lc[e + 5] * 64 + t];
            f16x8 h6 = H8[(size_t)lc[e + 6] * 64 + t];
            f16x8 h7 = H8[(size_t)lc[e + 7] * 64 + t];
            float w0 = lw[e],     w1 = lw[e + 1], w2 = lw[e + 2], w3 = lw[e + 3];
            float w4 = lw[e + 4], w5 = lw[e + 5], w6 = lw[e + 6], w7 = lw[e + 7];
            a0 += w0*(float)h0[0] + w1*(float)h1[0] + w2*(float)h2[0] + w3*(float)h3[0]
                + w4*(float)h4[0] + w5*(float)h5[0] + w6*(float)h6[0] + w7*(float)h7[0];
            a1 += w0*(float)h0[1] + w1*(float)h1[1] + w2*(float)h2[1] + w3*(float)h3[1]
                + w4*(float)h4[1] + w5*(float)h5[1] + w6*(float)h6[1] + w7*(float)h7[1];
            a2 += w0*(float)h0[2] + w1*(float)h1[2] + w2*(float)h2[2] + w3*(float)h3[2]
                + w4*(float)h4[2] + w5*(float)h5[2] + w6*(float)h6[2] + w7*(float)h7[2];
            a3 += w0*(float)h0[3] + w1*(float)h1[3] + w2*(float)h2[3] + w3*(float)h3[3]
                + w4*(float)h4[3] + w5*(float)h5[3] + w6*(float)h6[3] + w7*(float)h7[3];
            a4 += w0*(float)h0[4] + w1*(float)h1[4] + w2*(float)h2[4] + w3*(float)h3[4]
                + w4*(float)h4[4] + w5*(float)h5[4] + w6*(float)h6[4] + w7*(float)h7[4];
            a5 += w0*(float)h0[5] + w1*(float)h1[5] + w2*(float)h2[5] + w3*(float)h3[5]
                + w4*(float)h4[5] + w5*(float)h5[5] + w6*(float)h6[5] + w7*(float)h7[5];
            a6 += w0*(float)h0[6] + w1*(float)h1[6] + w2*(float)h2[6] + w3*(float)h3[6]
                + w4*(float)h4[6] + w5*(float)h5[6] + w6*(float)h6[6] + w7*(float)h7[6];
            a7 += w0*(float)h0[7] + w1*(float)h1[7] + w2*(float)h2[7] + w3*(float)h3[7]
                + w4*(float)h4[7] + w5*(float)h5[7] + w6*(float)h6[7] + w7*(float)h7[7];
        }
        for (; e < nn; ++e) {
            f16x8 h = H8[(size_t)lc[e] * 64 + t]; float w = lw[e];
            a0 += w * (float)h[0]; a1 += w * (float)h[1];
            a2 += w * (float)h[2]; a3 += w * (float)h[3];
            a4 += w * (float)h[4]; a5 += w * (float)h[5];
            a6 += w * (float)h[6]; a7 += w * (float)h[7];
        }
    }
    const float4* b4 = (const float4*)bias;
    float4 blo = b4[t * 2], bhi = b4[t * 2 + 1];
    a0 += blo.x; a1 += blo.y; a2 += blo.z; a3 += blo.w;
    a4 += bhi.x; a5 += bhi.y; a6 += bhi.z; a7 += bhi.w;
    if (relu) {
        a0 = fmaxf(a0, 0.f); a1 = fmaxf(a1, 0.f); a2 = fmaxf(a2, 0.f); a3 = fmaxf(a3, 0.f);
        a4 = fmaxf(a4, 0.f); a5 = fmaxf(a5, 0.f); a6 = fmaxf(a6, 0.f); a7 = fmaxf(a7, 0.f);
    }
    f16x8 o = { (_Float16)a0, (_Float16)a1, (_Float16)a2, (_Float16)a3,
                (_Float16)a4, (_Float16)a5, (_Float16)a6, (_Float16)a7 };
    ((f16x8*)out)[(size_t)row * 64 + t] = o;
}

// ---------------- SpMM K=64 fp16 + bias + softmax, one wave per dst row ----------------

__global__ __launch_bounds__(256) void k_spmm64_softmax(const int* __restrict__ rowp,
                                                        const int* __restrict__ ecol,
                                                        const float* __restrict__ ew,
                                                        const _Float16* __restrict__ H,
                                                        const float* __restrict__ bias,
                                                        float* __restrict__ out, int n) {
    int wid  = threadIdx.x >> 6;
    int lane = threadIdx.x & 63;
    int row  = blockIdx.x * 4 + wid;
    if (row >= n) return;
    int s0 = rowp[row], s1 = rowp[row + 1];
    float acc = 0.f;
    int e = s0;
    for (; e + 4 <= s1; e += 4) {
        float h0 = (float)H[(size_t)ecol[e]     * 64 + lane];
        float h1 = (float)H[(size_t)ecol[e + 1] * 64 + lane];
        float h2 = (float)H[(size_t)ecol[e + 2] * 64 + lane];
        float h3 = (float)H[(size_t)ecol[e + 3] * 64 + lane];
        acc += ew[e] * h0 + ew[e + 1] * h1 + ew[e + 2] * h2 + ew[e + 3] * h3;
    }
    for (; e < s1; ++e)
        acc += ew[e] * (float)H[(size_t)ecol[e] * 64 + lane];
    acc += bias[lane];
    float m = acc;
    for (int d = 32; d > 0; d >>= 1) m = fmaxf(m, __shfl_xor(m, d));
    float p = __expf(acc - m);
    float s = p;
    for (int d = 32; d > 0; d >>= 1) s += __shfl_xor(s, d);
    __builtin_nontemporal_store(p / s, out + (size_t)row * 64 + lane);
}

// ---------------- launch ----------------

extern "C" void kernel_launch(void* const* d_in, const int* in_sizes, int n_in,
                              void* d_out, int out_size, void* d_ws, size_t ws_size,
                              hipStream_t stream) {
    const float* X    = (const float*)d_in[0];
    const int*   esrc = (const int*)d_in[1];
    const int*   edst = (const int*)d_in[2];
    const float* ewin = (const float*)d_in[3];
    const float* W0   = (const float*)d_in[4];
    const float* b0   = (const float*)d_in[5];
    const float* W1   = (const float*)d_in[6];
    const float* b1   = (const float*)d_in[7];
    const float* W2   = (const float*)d_in[8];
    const float* b2   = (const float*)d_in[9];
    float* out = (float*)d_out;

    const int N = GN;
    const int E = GE;

    uint8_t* p = (uint8_t*)d_ws;
    auto alloc = [&](size_t bytes) -> void* {
        void* r = (void*)p;
        p += (bytes + 255) & ~(size_t)255;
        return r;
    };
    _Float16* bufM  = (_Float16*)alloc((size_t)N * 512 * 2);   // GEMM out (fp16, gather table)
    _Float16* bufG  = (_Float16*)alloc((size_t)N * 512 * 2);   // spmm out H (fp16, next A)
    _Float16* bufC3 = (_Float16*)alloc((size_t)N * 64 * 2);    // layer-3 logits pre-agg (fp16)
    _Float16* W0th  = (_Float16*)alloc((size_t)512 * 512 * 2);
    _Float16* W0tl  = (_Float16*)alloc((size_t)512 * 512 * 2);
    _Float16* W1th  = (_Float16*)alloc((size_t)512 * 512 * 2);
    _Float16* W1tl  = (_Float16*)alloc((size_t)512 * 512 * 2);
    _Float16* W2th  = (_Float16*)alloc((size_t)64 * 512 * 2);
    _Float16* W2tl  = (_Float16*)alloc((size_t)64 * 512 * 2);
    int*   cnt     = (int*)alloc((size_t)N * 4);
    int*   row_ptr = (int*)alloc((size_t)(N + 1) * 4);
    int*   cursor  = (int*)alloc((size_t)N * 4);
    int*   ecol    = (int*)alloc((size_t)E * 4);
    float* ewv     = (float*)alloc((size_t)E * 4);
    int*   bsum    = (int*)alloc(1024 * 4);
    int*   boff    = (int*)alloc(1024 * 4);

    // CSR by dst
    int nch = (N + 511) / 512;
    k_zero<<<(N + 255) / 256, 256, 0, stream>>>(cnt, N);
    k_hist<<<2048, 256, 0, stream>>>(edst, cnt, E);
    k_chunksum<<<nch, 256, 0, stream>>>(cnt, bsum, N);
    k_scanb<<<1, 64, 0, stream>>>(bsum, boff, nch, row_ptr, N);
    k_scanw<<<nch, 512, 0, stream>>>(cnt, boff, row_ptr, cursor, N);
    k_scatter<<<2048, 256, 0, stream>>>(esrc, edst, ewin, cursor, ecol, ewv, E);

    // weight split-transpose (hi/lo fp16)
    k_transp_split<<<dim3(16, 16), dim3(32, 8), 0, stream>>>(W0, W0th, W0tl, 512, 512);
    k_transp_split<<<dim3(16, 16), dim3(32, 8), 0, stream>>>(W1, W1th, W1tl, 512, 512);
    k_transp_split<<<dim3(2, 16),  dim3(32, 8), 0, stream>>>(W2, W2th, W2tl, 512, 64);

    int gy = (N + 127) / 128;
    // layer 1: M = X @ W0 (fp32-A split, X never rounded)
    k_gemm_split<128, _Float16><<<dim3(4, gy), 256, 0, stream>>>(X, W0th, W0tl, bufM, N, 512);
    k_spmm512_h2h<<<N, 64, 0, stream>>>(row_ptr, ecol, ewv, bufM, b0, bufG, 1);
    // layer 2: A = H1 (fp16), 2-MFMA variant
    k_gemm_f16w2<128, _Float16><<<dim3(4, gy), 256, 0, stream>>>(bufG, W1th, W1tl, bufM, N, 512);
    k_spmm512_h2h<<<N, 64, 0, stream>>>(row_ptr, ecol, ewv, bufM, b1, bufG, 1);
    // layer 3 + softmax (fp16 logits table, fp32 softmax)
    k_gemm_f16w2<64, _Float16><<<dim3(1, gy), 256, 0, stream>>>(bufG, W2th, W2tl, bufC3, N, 64);
    k_spmm64_softmax<<<(N + 3) / 4, 256, 0, stream>>>(row_ptr, ecol, ewv, bufC3, b2, out, N);
}

// Round 8
// 1668.336 us; speedup vs baseline: 2.1620x; 1.0242x over previous
//
#include <hip/hip_runtime.h>
#include <hip/hip_bf16.h>
#include <cstdint>
#include <cstddef>

#define GN 100000
#define GE 3200000

typedef __attribute__((ext_vector_type(8))) _Float16 f16x8;
typedef __attribute__((ext_vector_type(4))) _Float16 f16x4;
typedef __attribute__((ext_vector_type(4))) float f32x4;

// ---------------- CSR build ----------------

__global__ void k_zero(int* __restrict__ p, int n) {
    int i = blockIdx.x * blockDim.x + threadIdx.x;
    if (i < n) p[i] = 0;
}

__global__ void k_hist(const int* __restrict__ dst, int* __restrict__ cnt, int e) {
    for (int i = blockIdx.x * blockDim.x + threadIdx.x; i < e; i += gridDim.x * blockDim.x)
        atomicAdd(&cnt[dst[i]], 1);
}

__global__ void k_chunksum(const int* __restrict__ cnt, int* __restrict__ bsum, int n) {
    __shared__ int s[256];
    int b = blockIdx.x, t = threadIdx.x;
    int i0 = b * 512;
    int v = 0;
    int i1 = i0 + t;        if (i1 < n) v += cnt[i1];
    int i2 = i0 + 256 + t;  if (i2 < n) v += cnt[i2];
    s[t] = v; __syncthreads();
    for (int d = 128; d > 0; d >>= 1) {
        if (t < d) s[t] += s[t + d];
        __syncthreads();
    }
    if (t == 0) bsum[b] = s[0];
}

__global__ void k_scanb(const int* __restrict__ bsum, int* __restrict__ boff, int nb,
                        int* __restrict__ row_ptr, int n) {
    if (threadIdx.x == 0 && blockIdx.x == 0) {
        int acc = 0;
        for (int b = 0; b < nb; b++) { boff[b] = acc; acc += bsum[b]; }
        row_ptr[n] = acc;
    }
}

__global__ void k_scanw(const int* __restrict__ cnt, const int* __restrict__ boff,
                        int* __restrict__ row_ptr, int* __restrict__ cursor, int n) {
    __shared__ int s[512];
    int b = blockIdx.x, t = threadIdx.x;
    int i = b * 512 + t;
    int x = (i < n) ? cnt[i] : 0;
    s[t] = x; __syncthreads();
    for (int d = 1; d < 512; d <<= 1) {
        int v = (t >= d) ? s[t - d] : 0;
        __syncthreads();
        s[t] += v;
        __syncthreads();
    }
    int excl = s[t] - x + boff[b];
    if (i < n) { row_ptr[i] = excl; cursor[i] = excl; }
}

__global__ void k_scatter(const int* __restrict__ src, const int* __restrict__ dst,
                          const float* __restrict__ w, int* __restrict__ cursor,
                          int* __restrict__ ecol, float* __restrict__ ew, int e) {
    for (int i = blockIdx.x * blockDim.x + threadIdx.x; i < e; i += gridDim.x * blockDim.x) {
        int d = dst[i];
        int p = atomicAdd(&cursor[d], 1);
        ecol[p] = src[i];
        ew[p]   = w[i];
    }
}

// ---------------- W[K][M] fp32 -> split-transposed Wth/Wtl[M][K] fp16 ----------------

__global__ void k_transp_split(const float* __restrict__ W,
                               _Float16* __restrict__ Wth, _Float16* __restrict__ Wtl,
                               int K, int M) {
    __shared__ float tile[32][33];
    int bx = blockIdx.x * 32;  // M dim
    int by = blockIdx.y * 32;  // K dim
    int tx = threadIdx.x, ty = threadIdx.y;
    for (int i = ty; i < 32; i += 8)
        tile[i][tx] = W[(size_t)(by + i) * M + bx + tx];
    __syncthreads();
    for (int i = ty; i < 32; i += 8) {
        float w = tile[tx][i];
        _Float16 h = (_Float16)w;
        _Float16 l = (_Float16)(w - (float)h);
        Wth[(size_t)(bx + i) * K + by + tx] = h;
        Wtl[(size_t)(bx + i) * K + by + tx] = l;
    }
}

// ---------------- split fp16 MFMA GEMM (fp32 A): C = A @ Bt^T (layer 1) ----------------

template<int BN, typename OutT>
__global__ __launch_bounds__(256, 2) void k_gemm_split(const float* __restrict__ A,
                                                       const _Float16* __restrict__ Bth,
                                                       const _Float16* __restrict__ Btl,
                                                       OutT* __restrict__ C,
                                                       int n, int m) {
    constexpr int NI  = BN / 32;
    constexpr int BIT = BN / 32;
    __shared__ _Float16 Ash[128 * 64];
    __shared__ _Float16 Asl[128 * 64];
    __shared__ _Float16 Bsh[BN * 64];
    __shared__ _Float16 Bsl[BN * 64];
    int tid = threadIdx.x;
    int wv = tid >> 6, lane = tid & 63;
    int wr = wv >> 1, wc = wv & 1;
    int r0 = blockIdx.y * 128;
    int c0 = blockIdx.x * BN;

    float4 areg[8];
    f16x8 bregh[BIT], bregl[BIT];
    f32x4 acc[4][NI];
    #pragma unroll
    for (int i = 0; i < 4; i++)
        #pragma unroll
        for (int j = 0; j < NI; j++)
            acc[i][j] = (f32x4){0.f, 0.f, 0.f, 0.f};

    auto aload = [&](int kt) {
        #pragma unroll
        for (int i = 0; i < 8; ++i) {
            int q = tid + 256 * i;
            int row = q >> 4, c4 = q & 15;
            int gr = r0 + row; if (gr >= n) gr = n - 1;
            areg[i] = *(const float4*)(A + (size_t)gr * 512 + kt * 64 + c4 * 4);
        }
        #pragma unroll
        for (int i = 0; i < BIT; ++i) {
            int q = tid + 256 * i;
            int col = q >> 3, c = q & 7;
            size_t off = (size_t)(c0 + col) * 512 + kt * 64 + c * 8;
            bregh[i] = *(const f16x8*)(Bth + off);
            bregl[i] = *(const f16x8*)(Btl + off);
        }
    };

    aload(0);
    for (int kt = 0; kt < 8; ++kt) {
        __syncthreads();
        #pragma unroll
        for (int i = 0; i < 8; ++i) {
            int q = tid + 256 * i;
            int row = q >> 4, c4 = q & 15;
            int g = c4 ^ ((row & 7) << 1);
            float4 a = areg[i];
            _Float16 hx = (_Float16)a.x, hy = (_Float16)a.y;
            _Float16 hz = (_Float16)a.z, hw = (_Float16)a.w;
            f16x4 h = { hx, hy, hz, hw };
            f16x4 l = { (_Float16)(a.x - (float)hx), (_Float16)(a.y - (float)hy),
                        (_Float16)(a.z - (float)hz), (_Float16)(a.w - (float)hw) };
            *(f16x4*)&Ash[row * 64 + g * 4] = h;
            *(f16x4*)&Asl[row * 64 + g * 4] = l;
        }
        #pragma unroll
        for (int i = 0; i < BIT; ++i) {
            int q = tid + 256 * i;
            int col = q >> 3, c = q & 7;
            int idx = col * 64 + ((c ^ (col & 7)) * 8);
            *(f16x8*)&Bsh[idx] = bregh[i];
            *(f16x8*)&Bsl[idx] = bregl[i];
        }
        __syncthreads();
        if (kt < 7) aload(kt + 1);
        #pragma unroll
        for (int ks = 0; ks < 2; ++ks) {
            f16x8 afh[4], afl[4], bfh[NI], bfl[NI];
            int cch = ks * 4 + (lane >> 4);
            #pragma unroll
            for (int mi = 0; mi < 4; ++mi) {
                int row = wr * 64 + mi * 16 + (lane & 15);
                int idx = row * 64 + (((cch * 2) ^ ((row & 7) << 1)) * 4);
                afh[mi] = *(const f16x8*)&Ash[idx];
                afl[mi] = *(const f16x8*)&Asl[idx];
            }
            #pragma unroll
            for (int ni = 0; ni < NI; ++ni) {
                int col = wc * (BN / 2) + ni * 16 + (lane & 15);
                int idx = col * 64 + ((cch ^ (col & 7)) * 8);
                bfh[ni] = *(const f16x8*)&Bsh[idx];
                bfl[ni] = *(const f16x8*)&Bsl[idx];
            }
            #pragma unroll
            for (int mi = 0; mi < 4; ++mi)
                #pragma unroll
                for (int ni = 0; ni < NI; ++ni) {
                    acc[mi][ni] = __builtin_amdgcn_mfma_f32_16x16x32_f16(
                        afh[mi], bfl[ni], acc[mi][ni], 0, 0, 0);
                    acc[mi][ni] = __builtin_amdgcn_mfma_f32_16x16x32_f16(
                        afl[mi], bfh[ni], acc[mi][ni], 0, 0, 0);
                    acc[mi][ni] = __builtin_amdgcn_mfma_f32_16x16x32_f16(
                        afh[mi], bfh[ni], acc[mi][ni], 0, 0, 0);
                }
        }
    }

    #pragma unroll
    for (int mi = 0; mi < 4; ++mi) {
        #pragma unroll
        for (int j = 0; j < 4; ++j) {
            int gr = r0 + wr * 64 + mi * 16 + (lane >> 4) * 4 + j;
            if (gr < n) {
                #pragma unroll
                for (int ni = 0; ni < NI; ++ni) {
                    int gc = c0 + wc * (BN / 2) + ni * 16 + (lane & 15);
                    C[(size_t)gr * m + gc] = (OutT)acc[mi][ni][j];
                }
            }
        }
    }
}

// ---------------- fp16-A, split-W MFMA GEMM (layers 2,3) ----------------

template<int BN, typename OutT>
__global__ __launch_bounds__(256, 2) void k_gemm_f16w2(const _Float16* __restrict__ A,
                                                       const _Float16* __restrict__ Bth,
                                                       const _Float16* __restrict__ Btl,
                                                       OutT* __restrict__ C,
                                                       int n, int m) {
    constexpr int NI  = BN / 32;
    constexpr int BIT = BN / 32;
    __shared__ _Float16 As[128 * 64];
    __shared__ _Float16 Bsh[BN * 64];
    __shared__ _Float16 Bsl[BN * 64];
    int tid = threadIdx.x;
    int wv = tid >> 6, lane = tid & 63;
    int wr = wv >> 1, wc = wv & 1;
    int r0 = blockIdx.y * 128;
    int c0 = blockIdx.x * BN;

    f16x8 areg[4], bregh[BIT], bregl[BIT];
    f32x4 acc[4][NI];
    #pragma unroll
    for (int i = 0; i < 4; i++)
        #pragma unroll
        for (int j = 0; j < NI; j++)
            acc[i][j] = (f32x4){0.f, 0.f, 0.f, 0.f};

    auto aload = [&](int kt) {
        #pragma unroll
        for (int i = 0; i < 4; ++i) {
            int q = tid + 256 * i;
            int row = q >> 3, c = q & 7;
            int gr = r0 + row; if (gr >= n) gr = n - 1;
            areg[i] = *(const f16x8*)(A + (size_t)gr * 512 + kt * 64 + c * 8);
        }
        #pragma unroll
        for (int i = 0; i < BIT; ++i) {
            int q = tid + 256 * i;
            int col = q >> 3, c = q & 7;
            size_t off = (size_t)(c0 + col) * 512 + kt * 64 + c * 8;
            bregh[i] = *(const f16x8*)(Bth + off);
            bregl[i] = *(const f16x8*)(Btl + off);
        }
    };

    aload(0);
    for (int kt = 0; kt < 8; ++kt) {
        __syncthreads();
        #pragma unroll
        for (int i = 0; i < 4; ++i) {
            int q = tid + 256 * i;
            int row = q >> 3, c = q & 7;
            *(f16x8*)&As[row * 64 + ((c ^ (row & 7)) * 8)] = areg[i];
        }
        #pragma unroll
        for (int i = 0; i < BIT; ++i) {
            int q = tid + 256 * i;
            int col = q >> 3, c = q & 7;
            int idx = col * 64 + ((c ^ (col & 7)) * 8);
            *(f16x8*)&Bsh[idx] = bregh[i];
            *(f16x8*)&Bsl[idx] = bregl[i];
        }
        __syncthreads();
        if (kt < 7) aload(kt + 1);
        #pragma unroll
        for (int ks = 0; ks < 2; ++ks) {
            f16x8 af[4], bfh[NI], bfl[NI];
            int cch = ks * 4 + (lane >> 4);
            #pragma unroll
            for (int mi = 0; mi < 4; ++mi) {
                int row = wr * 64 + mi * 16 + (lane & 15);
                af[mi] = *(const f16x8*)&As[row * 64 + ((cch ^ (row & 7)) * 8)];
            }
            #pragma unroll
            for (int ni = 0; ni < NI; ++ni) {
                int col = wc * (BN / 2) + ni * 16 + (lane & 15);
                int idx = col * 64 + ((cch ^ (col & 7)) * 8);
                bfh[ni] = *(const f16x8*)&Bsh[idx];
                bfl[ni] = *(const f16x8*)&Bsl[idx];
            }
            #pragma unroll
            for (int mi = 0; mi < 4; ++mi)
                #pragma unroll
                for (int ni = 0; ni < NI; ++ni) {
                    acc[mi][ni] = __builtin_amdgcn_mfma_f32_16x16x32_f16(
                        af[mi], bfl[ni], acc[mi][ni], 0, 0, 0);
                    acc[mi][ni] = __builtin_amdgcn_mfma_f32_16x16x32_f16(
                        af[mi], bfh[ni], acc[mi][ni], 0, 0, 0);
                }
        }
    }

    #pragma unroll
    for (int mi = 0; mi < 4; ++mi) {
        #pragma unroll
        for (int j = 0; j < 4; ++j) {
            int gr = r0 + wr * 64 + mi * 16 + (lane >> 4) * 4 + j;
            if (gr < n) {
                #pragma unroll
                for (int ni = 0; ni < NI; ++ni) {
                    int gc = c0 + wc * (BN / 2) + ni * 16 + (lane & 15);
                    C[(size_t)gr * m + gc] = (OutT)acc[mi][ni][j];
                }
            }
        }
    }
}

// ---------------- SpMM K=512, 256-col slice: fp16 gather -> fp16 out ----------------
// Global column slicing: pass `slice` covers cols [slice*256, slice*256+256).
// Halves per-pass row footprint (512 B/edge) and active table slice (51 MB) —
// capacity-sensitivity experiment for the beyond-L2 fetch plateau.

__global__ __launch_bounds__(64) void k_spmm512_slice(const int* __restrict__ rowp,
                                                      const int* __restrict__ ecol,
                                                      const float* __restrict__ ew,
                                                      const _Float16* __restrict__ H,
                                                      const float* __restrict__ bias,
                                                      _Float16* __restrict__ out,
                                                      int relu, int slice) {
    int row = blockIdx.x;
    int t = threadIdx.x;                 // 64 threads, each owns 4 cols (f16x4) of the slice
    int s0 = rowp[row], s1 = rowp[row + 1];
    const f16x4* H4 = (const f16x4*)H;   // row stride 128 vectors
    int vo = slice * 64 + t;             // vector offset within a row
    float a0 = 0.f, a1 = 0.f, a2 = 0.f, a3 = 0.f;
    __shared__ int   lc[64];
    __shared__ float lw[64];
    for (int base = s0; base < s1; base += 64) {
        int nn = s1 - base; if (nn > 64) nn = 64;
        __syncthreads();
        if (t < nn) {
            lc[t] = __builtin_nontemporal_load(ecol + base + t);
            lw[t] = __builtin_nontemporal_load(ew + base + t);
        }
        __syncthreads();
        int e = 0;
        for (; e + 8 <= nn; e += 8) {      // 8 outstanding 512B wave-gathers
            f16x4 h0 = H4[(size_t)lc[e]     * 128 + vo];
            f16x4 h1 = H4[(size_t)lc[e + 1] * 128 + vo];
            f16x4 h2 = H4[(size_t)lc[e + 2] * 128 + vo];
            f16x4 h3 = H4[(size_t)lc[e + 3] * 128 + vo];
            f16x4 h4 = H4[(size_t)lc[e + 4] * 128 + vo];
            f16x4 h5 = H4[(size_t)lc[e + 5] * 128 + vo];
            f16x4 h6 = H4[(size_t)lc[e + 6] * 128 + vo];
            f16x4 h7 = H4[(size_t)lc[e + 7] * 128 + vo];
            float w0 = lw[e],     w1 = lw[e + 1], w2 = lw[e + 2], w3 = lw[e + 3];
            float w4 = lw[e + 4], w5 = lw[e + 5], w6 = lw[e + 6], w7 = lw[e + 7];
            a0 += w0*(float)h0[0] + w1*(float)h1[0] + w2*(float)h2[0] + w3*(float)h3[0]
                + w4*(float)h4[0] + w5*(float)h5[0] + w6*(float)h6[0] + w7*(float)h7[0];
            a1 += w0*(float)h0[1] + w1*(float)h1[1] + w2*(float)h2[1] + w3*(float)h3[1]
                + w4*(float)h4[1] + w5*(float)h5[1] + w6*(float)h6[1] + w7*(float)h7[1];
            a2 += w0*(float)h0[2] + w1*(float)h1[2] + w2*(float)h2[2] + w3*(float)h3[2]
                + w4*(float)h4[2] + w5*(float)h5[2] + w6*(float)h6[2] + w7*(float)h7[2];
            a3 += w0*(float)h0[3] + w1*(float)h1[3] + w2*(float)h2[3] + w3*(float)h3[3]
                + w4*(float)h4[3] + w5*(float)h5[3] + w6*(float)h6[3] + w7*(float)h7[3];
        }
        for (; e < nn; ++e) {
            f16x4 h = H4[(size_t)lc[e] * 128 + vo]; float w = lw[e];
            a0 += w * (float)h[0]; a1 += w * (float)h[1];
            a2 += w * (float)h[2]; a3 += w * (float)h[3];
        }
    }
    float4 b = ((const float4*)bias)[vo];
    a0 += b.x; a1 += b.y; a2 += b.z; a3 += b.w;
    if (relu) {
        a0 = fmaxf(a0, 0.f); a1 = fmaxf(a1, 0.f);
        a2 = fmaxf(a2, 0.f); a3 = fmaxf(a3, 0.f);
    }
    f16x4 o = { (_Float16)a0, (_Float16)a1, (_Float16)a2, (_Float16)a3 };
    ((f16x4*)out)[(size_t)row * 128 + vo] = o;
}

// ---------------- SpMM K=64 fp32 + bias + softmax, one wave per dst row ----------------

__global__ __launch_bounds__(256) void k_spmm64_softmax(const int* __restrict__ rowp,
                                                        const int* __restrict__ ecol,
                                                        const float* __restrict__ ew,
                                                        const float* __restrict__ H,
                                                        const float* __restrict__ bias,
                                                        float* __restrict__ out, int n) {
    int wid  = threadIdx.x >> 6;
    int lane = threadIdx.x & 63;
    int row  = blockIdx.x * 4 + wid;
    if (row >= n) return;
    int s0 = rowp[row], s1 = rowp[row + 1];
    float acc = 0.f;
    int e = s0;
    for (; e + 4 <= s1; e += 4) {
        float h0 = H[(size_t)ecol[e]     * 64 + lane];
        float h1 = H[(size_t)ecol[e + 1] * 64 + lane];
        float h2 = H[(size_t)ecol[e + 2] * 64 + lane];
        float h3 = H[(size_t)ecol[e + 3] * 64 + lane];
        acc += ew[e] * h0 + ew[e + 1] * h1 + ew[e + 2] * h2 + ew[e + 3] * h3;
    }
    for (; e < s1; ++e)
        acc += ew[e] * H[(size_t)ecol[e] * 64 + lane];
    acc += bias[lane];
    float m = acc;
    for (int d = 32; d > 0; d >>= 1) m = fmaxf(m, __shfl_xor(m, d));
    float p = __expf(acc - m);
    float s = p;
    for (int d = 32; d > 0; d >>= 1) s += __shfl_xor(s, d);
    __builtin_nontemporal_store(p / s, out + (size_t)row * 64 + lane);
}

// ---------------- launch ----------------

extern "C" void kernel_launch(void* const* d_in, const int* in_sizes, int n_in,
                              void* d_out, int out_size, void* d_ws, size_t ws_size,
                              hipStream_t stream) {
    const float* X    = (const float*)d_in[0];
    const int*   esrc = (const int*)d_in[1];
    const int*   edst = (const int*)d_in[2];
    const float* ewin = (const float*)d_in[3];
    const float* W0   = (const float*)d_in[4];
    const float* b0   = (const float*)d_in[5];
    const float* W1   = (const float*)d_in[6];
    const float* b1   = (const float*)d_in[7];
    const float* W2   = (const float*)d_in[8];
    const float* b2   = (const float*)d_in[9];
    float* out = (float*)d_out;

    const int N = GN;
    const int E = GE;

    uint8_t* p = (uint8_t*)d_ws;
    auto alloc = [&](size_t bytes) -> void* {
        void* r = (void*)p;
        p += (bytes + 255) & ~(size_t)255;
        return r;
    };
    _Float16* bufM  = (_Float16*)alloc((size_t)N * 512 * 2);   // GEMM out (fp16, gather table)
    _Float16* bufG  = (_Float16*)alloc((size_t)N * 512 * 2);   // spmm out H (fp16, next A)
    float*    bufC3 = (float*)alloc((size_t)N * 64 * 4);       // layer-3 logits (fp32, margin)
    _Float16* W0th  = (_Float16*)alloc((size_t)512 * 512 * 2);
    _Float16* W0tl  = (_Float16*)alloc((size_t)512 * 512 * 2);
    _Float16* W1th  = (_Float16*)alloc((size_t)512 * 512 * 2);
    _Float16* W1tl  = (_Float16*)alloc((size_t)512 * 512 * 2);
    _Float16* W2th  = (_Float16*)alloc((size_t)64 * 512 * 2);
    _Float16* W2tl  = (_Float16*)alloc((size_t)64 * 512 * 2);
    int*   cnt     = (int*)alloc((size_t)N * 4);
    int*   row_ptr = (int*)alloc((size_t)(N + 1) * 4);
    int*   cursor  = (int*)alloc((size_t)N * 4);
    int*   ecol    = (int*)alloc((size_t)E * 4);
    float* ewv     = (float*)alloc((size_t)E * 4);
    int*   bsum    = (int*)alloc(1024 * 4);
    int*   boff    = (int*)alloc(1024 * 4);

    // CSR by dst
    int nch = (N + 511) / 512;
    k_zero<<<(N + 255) / 256, 256, 0, stream>>>(cnt, N);
    k_hist<<<2048, 256, 0, stream>>>(edst, cnt, E);
    k_chunksum<<<nch, 256, 0, stream>>>(cnt, bsum, N);
    k_scanb<<<1, 64, 0, stream>>>(bsum, boff, nch, row_ptr, N);
    k_scanw<<<nch, 512, 0, stream>>>(cnt, boff, row_ptr, cursor, N);
    k_scatter<<<2048, 256, 0, stream>>>(esrc, edst, ewin, cursor, ecol, ewv, E);

    // weight split-transpose (hi/lo fp16)
    k_transp_split<<<dim3(16, 16), dim3(32, 8), 0, stream>>>(W0, W0th, W0tl, 512, 512);
    k_transp_split<<<dim3(16, 16), dim3(32, 8), 0, stream>>>(W1, W1th, W1tl, 512, 512);
    k_transp_split<<<dim3(2, 16),  dim3(32, 8), 0, stream>>>(W2, W2th, W2tl, 512, 64);

    int gy = (N + 127) / 128;
    // layer 1: M = X @ W0 (fp32-A split, X never rounded); spmm in 2 column slices
    k_gemm_split<128, _Float16><<<dim3(4, gy), 256, 0, stream>>>(X, W0th, W0tl, bufM, N, 512);
    k_spmm512_slice<<<N, 64, 0, stream>>>(row_ptr, ecol, ewv, bufM, b0, bufG, 1, 0);
    k_spmm512_slice<<<N, 64, 0, stream>>>(row_ptr, ecol, ewv, bufM, b0, bufG, 1, 1);
    // layer 2
    k_gemm_f16w2<128, _Float16><<<dim3(4, gy), 256, 0, stream>>>(bufG, W1th, W1tl, bufM, N, 512);
    k_spmm512_slice<<<N, 64, 0, stream>>>(row_ptr, ecol, ewv, bufM, b1, bufG, 1, 0);
    k_spmm512_slice<<<N, 64, 0, stream>>>(row_ptr, ecol, ewv, bufM, b1, bufG, 1, 1);
    // layer 3 + softmax (fp32 logits)
    k_gemm_f16w2<64, float><<<dim3(1, gy), 256, 0, stream>>>(bufG, W2th, W2tl, bufC3, N, 64);
    k_spmm64_softmax<<<(N + 3) / 4, 256, 0, stream>>>(row_ptr, ecol, ewv, bufC3, b2, out, N);
}